// Round 4
// baseline (387.928 us; speedup 1.0000x reference)
//
#include <hip/hip_runtime.h>
#include <math.h>

#define N_NODES 50000
#define N_PAD   50016                 // padded to 32-row gemm tiles
#define N_EDGES 800000
#define E_TOT   (N_EDGES + N_NODES)   // edges + self-loops = 850000
#define F_IN    256
#define NHEAD   8
#define CH      32
#define HC      256                   // NHEAD*CH
#define OUT_C   40
#define NEG_SLOPE 0.2f
#define SCAN_BLOCKS ((N_NODES + 255) / 256)   // 196
#define G_WCVT  ((HC * F_IN + 255) / 256)            // 256
#define G_WCVT2 ((HC * CH + 255) / 256)              // 32
#define NRANGE  8                     // XCD count: dst-range affinity bins
#define RANGE_SZ (N_NODES / NRANGE)   // 6250
#define BIN_CHUNK 2048
#define G_BINCH ((E_TOT + BIN_CHUNK - 1) / BIN_CHUNK)   // 416

typedef unsigned short u16;
typedef unsigned int   u32;
typedef unsigned char  u8;
typedef __attribute__((ext_vector_type(8))) short bf16x8;   // 4 VGPRs
typedef __attribute__((ext_vector_type(4))) float f32x4;
typedef __attribute__((ext_vector_type(2))) float f32x2;

__device__ __forceinline__ u16 f2bf(float f) {
    union { u32 u; float f; } x; x.f = f;
    u32 u = x.u;
    return (u16)((u + 0x7fffu + ((u >> 16) & 1u)) >> 16);   // round-nearest-even
}
__device__ __forceinline__ float bflo(u32 v) {
    union { u32 u; float f; } x; x.u = v << 16; return x.f;
}
// fp8 e4m3 encode (1 byte) / packed decode (2 floats per op) — gfx950 native
__device__ __forceinline__ u8 f2fp8(float f) {
    return (u8)(__builtin_amdgcn_cvt_pk_fp8_f32(f, f, 0, false) & 0xff);
}
// two float4 -> bf16x8 (RNE, bit-identical to the old cvt path)
__device__ __forceinline__ bf16x8 pack_bf16x8(float4 a, float4 b) {
    bf16x8 r;
    r[0] = (short)f2bf(a.x); r[1] = (short)f2bf(a.y);
    r[2] = (short)f2bf(a.z); r[3] = (short)f2bf(a.w);
    r[4] = (short)f2bf(b.x); r[5] = (short)f2bf(b.y);
    r[6] = (short)f2bf(b.z); r[7] = (short)f2bf(b.w);
    return r;
}

// ht8 is fp8 e4m3 in NATURAL (head-major) layout: ht8[node*256 + h*32 + c].
// gemm stores are identity; in attn a 16-lane quarter reads one row as uint4.
// NOTE: f2fp8 of finite inputs saturates (never emits NaN bytes) — attn's
// stale-prefetch-register trick relies on decoded fp8 always being finite.

// ===== prep: W1->bf16^T, W2->bf16^T (tiny; x conversion fused into gemm1)
__global__ __launch_bounds__(256) void cvt_kernel(const float* __restrict__ W1,
        u16* __restrict__ Wt, const float* __restrict__ W2, u16* __restrict__ W2t) {
    int b = blockIdx.x;
    if (b < G_WCVT) {
        int t = b * 256 + threadIdx.x;               // 65536 total
        int n = t & 255, k = t >> 8;                 // coalesced reads
        Wt[(size_t)n * F_IN + k] = f2bf(W1[(size_t)k * HC + n]);
    } else {
        int t = (b - G_WCVT) * 256 + threadIdx.x;    // 8192 total
        if (t >= HC * CH) return;
        int n = t & 255, k = t >> 8;
        W2t[(size_t)n * CH + k] = f2bf(W2[(size_t)k * HC + n]);
    }
}

// ================= GEMM1 via MFMA bf16: ht8 = fp8(x @ W1), natural store
// r19: reads x fp32 directly and packs bf16 in-register (RNE f2bf, identical
// numerics) — kills the 25.6MB xb write + 25.6MB re-read of the old cvt path.
__global__ __launch_bounds__(256) void gemm1_mfma(const float* __restrict__ x,
        const u16* __restrict__ Wt, u8* __restrict__ ht8) {
    const int row0 = blockIdx.x * 32;
    const int t    = threadIdx.x;
    const int wave = t >> 6;
    const int lane = t & 63;
    const int l16  = lane & 15;
    const int quad = lane >> 4;
    const int nb   = wave * 64;

    f32x4 acc[2][4];
    #pragma unroll
    for (int m = 0; m < 2; ++m)
        #pragma unroll
        for (int n = 0; n < 4; ++n) acc[m][n] = (f32x4){0.f, 0.f, 0.f, 0.f};

    // clamp pad rows (x has exactly N_NODES rows; pad outputs are discarded)
    const int ar0 = min(row0 + l16, N_NODES - 1);
    const int ar1 = min(row0 + 16 + l16, N_NODES - 1);
    const float* a0p = x + (size_t)ar0 * F_IN;
    const float* a1p = x + (size_t)ar1 * F_IN;
    const u16*   bp  = Wt + (size_t)(nb + l16) * F_IN;   // N-tile stride 16*F_IN

    #pragma unroll 1
    for (int k0 = 0; k0 < F_IN; k0 += 32) {
        const int ko = k0 + quad * 8;
        float4 a0lo = *(const float4*)(a0p + ko);
        float4 a0hi = *(const float4*)(a0p + ko + 4);
        float4 a1lo = *(const float4*)(a1p + ko);
        float4 a1hi = *(const float4*)(a1p + ko + 4);
        bf16x8 a0 = pack_bf16x8(a0lo, a0hi);
        bf16x8 a1 = pack_bf16x8(a1lo, a1hi);
        bf16x8 b0 = *(const bf16x8*)(bp + 0 * 16 * F_IN + ko);
        bf16x8 b1 = *(const bf16x8*)(bp + 1 * 16 * F_IN + ko);
        bf16x8 b2 = *(const bf16x8*)(bp + 2 * 16 * F_IN + ko);
        bf16x8 b3 = *(const bf16x8*)(bp + 3 * 16 * F_IN + ko);
        acc[0][0] = __builtin_amdgcn_mfma_f32_16x16x32_bf16(a0, b0, acc[0][0], 0, 0, 0);
        acc[0][1] = __builtin_amdgcn_mfma_f32_16x16x32_bf16(a0, b1, acc[0][1], 0, 0, 0);
        acc[0][2] = __builtin_amdgcn_mfma_f32_16x16x32_bf16(a0, b2, acc[0][2], 0, 0, 0);
        acc[0][3] = __builtin_amdgcn_mfma_f32_16x16x32_bf16(a0, b3, acc[0][3], 0, 0, 0);
        acc[1][0] = __builtin_amdgcn_mfma_f32_16x16x32_bf16(a1, b0, acc[1][0], 0, 0, 0);
        acc[1][1] = __builtin_amdgcn_mfma_f32_16x16x32_bf16(a1, b1, acc[1][1], 0, 0, 0);
        acc[1][2] = __builtin_amdgcn_mfma_f32_16x16x32_bf16(a1, b2, acc[1][2], 0, 0, 0);
        acc[1][3] = __builtin_amdgcn_mfma_f32_16x16x32_bf16(a1, b3, acc[1][3], 0, 0, 0);
    }

    #pragma unroll
    for (int m = 0; m < 2; ++m) {
        #pragma unroll
        for (int r = 0; r < 4; ++r) {
            int row = row0 + m * 16 + quad * 4 + r;
            if (row < N_NODES) {
                u8* hr = ht8 + (size_t)row * HC;
                #pragma unroll
                for (int n = 0; n < 4; ++n) {
                    int col = nb + n * 16 + l16;
                    hr[col] = f2fp8(acc[m][n][r]);   // natural layout
                }
            }
        }
    }
}

// ================= GEMM2 via MFMA bf16: ht8 = fp8(hmb @ W2), K=32 single step
__global__ __launch_bounds__(256) void gemm2_mfma(const u16* __restrict__ hmb,
        const u16* __restrict__ W2t, u8* __restrict__ ht8) {
    const int row0 = blockIdx.x * 32;
    const int t    = threadIdx.x;
    const int wave = t >> 6;
    const int lane = t & 63;
    const int l16  = lane & 15;
    const int quad = lane >> 4;
    const int nb   = wave * 64;
    const int ko   = quad * 8;

    const u16* a0p = hmb + (size_t)(row0 + l16) * CH;
    const u16* a1p = a0p + 16 * CH;
    const u16* bp  = W2t + (size_t)(nb + l16) * CH;

    bf16x8 a0 = *(const bf16x8*)(a0p + ko);
    bf16x8 a1 = *(const bf16x8*)(a1p + ko);
    bf16x8 b0 = *(const bf16x8*)(bp + 0 * 16 * CH + ko);
    bf16x8 b1 = *(const bf16x8*)(bp + 1 * 16 * CH + ko);
    bf16x8 b2 = *(const bf16x8*)(bp + 2 * 16 * CH + ko);
    bf16x8 b3 = *(const bf16x8*)(bp + 3 * 16 * CH + ko);

    f32x4 z = (f32x4){0.f, 0.f, 0.f, 0.f};
    f32x4 acc[2][4];
    acc[0][0] = __builtin_amdgcn_mfma_f32_16x16x32_bf16(a0, b0, z, 0, 0, 0);
    acc[0][1] = __builtin_amdgcn_mfma_f32_16x16x32_bf16(a0, b1, z, 0, 0, 0);
    acc[0][2] = __builtin_amdgcn_mfma_f32_16x16x32_bf16(a0, b2, z, 0, 0, 0);
    acc[0][3] = __builtin_amdgcn_mfma_f32_16x16x32_bf16(a0, b3, z, 0, 0, 0);
    acc[1][0] = __builtin_amdgcn_mfma_f32_16x16x32_bf16(a1, b0, z, 0, 0, 0);
    acc[1][1] = __builtin_amdgcn_mfma_f32_16x16x32_bf16(a1, b1, z, 0, 0, 0);
    acc[1][2] = __builtin_amdgcn_mfma_f32_16x16x32_bf16(a1, b2, z, 0, 0, 0);
    acc[1][3] = __builtin_amdgcn_mfma_f32_16x16x32_bf16(a1, b3, z, 0, 0, 0);

    #pragma unroll
    for (int m = 0; m < 2; ++m) {
        #pragma unroll
        for (int r = 0; r < 4; ++r) {
            int row = row0 + m * 16 + quad * 4 + r;
            if (row < N_NODES) {
                u8* hr = ht8 + (size_t)row * HC;
                #pragma unroll
                for (int n = 0; n < 4; ++n) {
                    int col = nb + n * 16 + l16;
                    hr[col] = f2fp8(acc[m][n][r]);   // natural layout
                }
            }
        }
    }
}

// ================= alpha from fp8 ht (head-major): thread = node
__global__ __launch_bounds__(256) void alpha_t_kernel(const u8* __restrict__ ht8,
        const float* __restrict__ a_src, const float* __restrict__ a_dst,
        float* __restrict__ asrc, float* __restrict__ adst) {
    __shared__ float sas[HC], sad[HC];
    for (int i = threadIdx.x; i < HC; i += 256) {
        sas[i] = a_src[i];
        sad[i] = a_dst[i];
    }
    __syncthreads();
    int node = blockIdx.x * 256 + threadIdx.x;
    if (node >= N_NODES) return;
    const uint2* hp = (const uint2*)(ht8 + (size_t)node * HC);   // 32 uint2
    float s1[NHEAD], s2[NHEAD];
    #pragma unroll
    for (int h = 0; h < NHEAD; ++h) {
        float t1 = 0.f, t2 = 0.f;
        #pragma unroll
        for (int i = 0; i < 4; ++i) {
            uint2 v = hp[h * 4 + i];                  // channels i*8 .. i*8+7
            f32x2 p01 = __builtin_amdgcn_cvt_pk_f32_fp8(v.x, false);
            f32x2 p23 = __builtin_amdgcn_cvt_pk_f32_fp8(v.x, true);
            f32x2 p45 = __builtin_amdgcn_cvt_pk_f32_fp8(v.y, false);
            f32x2 p67 = __builtin_amdgcn_cvt_pk_f32_fp8(v.y, true);
            const float* s1p = &sas[h * CH + i * 8];  // broadcast (same addr)
            const float* s2p = &sad[h * CH + i * 8];
            t1 += p01.x * s1p[0] + p01.y * s1p[1] + p23.x * s1p[2] + p23.y * s1p[3]
                + p45.x * s1p[4] + p45.y * s1p[5] + p67.x * s1p[6] + p67.y * s1p[7];
            t2 += p01.x * s2p[0] + p01.y * s2p[1] + p23.x * s2p[2] + p23.y * s2p[3]
                + p45.x * s2p[4] + p45.y * s2p[5] + p67.x * s2p[6] + p67.y * s2p[7];
        }
        s1[h] = t1; s2[h] = t2;
    }
    float4* o1 = (float4*)(asrc + (size_t)node * NHEAD);
    float4* o2 = (float4*)(adst + (size_t)node * NHEAD);
    o1[0] = make_float4(s1[0], s1[1], s1[2], s1[3]);
    o1[1] = make_float4(s1[4], s1[5], s1[6], s1[7]);
    o2[0] = make_float4(s2[0], s2[1], s2[2], s2[3]);
    o2[1] = make_float4(s2[4], s2[5], s2[6], s2[7]);
}

// ================= CSR build =================
// r19: deg + scatter are XCD-AFFINE BINNED. Old scatter: 850k random 4B
// stores with writers on all 8 XCDs -> one 64B dirty-line coherence event
// per store (WRITE_SIZE 55MB, ~60us). Now blockIdx&7 selects a dst-range
// (round-robin dispatch puts all writers of a range on ONE XCD); lines stay
// dirty in the local L2 and write back once. Correct regardless of the
// actual block->XCD mapping (ranges are disjoint); cost is an 8x re-read of
// the dst column (~27MB coalesced).
__global__ __launch_bounds__(256) void deg_kernel(const int* __restrict__ ei,
        int* __restrict__ deg) {
    const int r  = blockIdx.x & (NRANGE - 1);
    const int ch = blockIdx.x >> 3;
    const int lo = r * RANGE_SZ, hi = lo + RANGE_SZ;
    int j0 = ch * BIN_CHUNK + threadIdx.x;
    #pragma unroll
    for (int i = 0; i < BIN_CHUNK / 256; ++i) {
        int j = j0 + i * 256;
        if (j < E_TOT) {
            int d = (j < N_EDGES) ? ei[N_EDGES + j] : (j - N_EDGES);
            if (d >= lo && d < hi) atomicAdd(&deg[d], 1);
        }
    }
}

__device__ __forceinline__ int wave_incl_scan(int v, int lane) {
    #pragma unroll
    for (int d = 1; d < 64; d <<= 1) {
        int u = __shfl_up(v, d, 64);
        if (lane >= d) v += u;
    }
    return v;
}

__global__ __launch_bounds__(256) void scan1_kernel(const int* __restrict__ deg,
        int* __restrict__ rowptr, int* __restrict__ partials) {
    const int t    = blockIdx.x * 256 + threadIdx.x;
    const int lane = threadIdx.x & 63;
    const int wid  = threadIdx.x >> 6;
    int v = (t < N_NODES) ? deg[t] : 0;
    int inc = wave_incl_scan(v, lane);
    __shared__ int wtot[4];
    if (lane == 63) wtot[wid] = inc;
    __syncthreads();
    int woff = 0;
    #pragma unroll
    for (int i = 0; i < 4; ++i) woff += (i < wid) ? wtot[i] : 0;
    if (t < N_NODES) rowptr[t] = inc - v + woff;      // block-local exclusive
    if (threadIdx.x == 255) partials[blockIdx.x] = woff + inc;  // block total
}

__global__ __launch_bounds__(256) void scan2_kernel(int* __restrict__ partials) {
    const int t    = threadIdx.x;
    const int lane = t & 63;
    const int wid  = t >> 6;
    int v = (t < SCAN_BLOCKS) ? partials[t] : 0;
    int inc = wave_incl_scan(v, lane);
    __shared__ int wtot[4];
    if (lane == 63) wtot[wid] = inc;
    __syncthreads();
    int woff = 0;
    #pragma unroll
    for (int i = 0; i < 4; ++i) woff += (i < wid) ? wtot[i] : 0;
    __syncthreads();
    if (t < SCAN_BLOCKS) partials[t] = inc - v + woff;
}

__global__ __launch_bounds__(256) void scan3_kernel(int* __restrict__ rowptr,
        int* __restrict__ cursor, const int* __restrict__ partials) {
    const int t = blockIdx.x * 256 + threadIdx.x;
    if (t < N_NODES) {
        int v = rowptr[t] + partials[blockIdx.x];
        rowptr[t] = v;
        cursor[t] = v;
    } else if (t == N_NODES) {
        rowptr[N_NODES] = E_TOT;
    }
}

__global__ __launch_bounds__(256) void scatter_kernel(const int* __restrict__ ei,
        int* __restrict__ cursor, u16* __restrict__ csr_src) {
    const int r  = blockIdx.x & (NRANGE - 1);
    const int ch = blockIdx.x >> 3;
    const int lo = r * RANGE_SZ, hi = lo + RANGE_SZ;
    int j0 = ch * BIN_CHUNK + threadIdx.x;
    #pragma unroll
    for (int i = 0; i < BIN_CHUNK / 256; ++i) {
        int j = j0 + i * 256;
        if (j < E_TOT) {
            int d = (j < N_EDGES) ? ei[N_EDGES + j] : (j - N_EDGES);
            if (d >= lo && d < hi) {
                int s = (j < N_EDGES) ? ei[j] : d;
                int pos = atomicAdd(&cursor[d], 1);
                csr_src[pos] = (u16)s;
            }
        }
    }
}

// ================= fused attention: one WAVE per dst node, QUARTER per edge.
// r18 structure kept (uniform trips, pk_fma, u16 csr) — r19 control kernel.
__global__ __launch_bounds__(256) void attn_kernel(const int* __restrict__ rowptr,
        const u16* __restrict__ csr_src, const float* __restrict__ asrc,
        const float* __restrict__ adst, const u8* __restrict__ ht8,
        const float* __restrict__ b, u16* __restrict__ out) {
    const int wid = (blockIdx.x * 256 + threadIdx.x) >> 6;   // dst node
    if (wid >= N_NODES) return;
    const int dst  = wid;
    const int lane = threadIdx.x & 63;
    const int q    = lane >> 4;          // quarter -> edge offset
    const int l16  = lane & 15;
    const int h    = l16 >> 1;           // owned head
    const float ad_own = adst[dst * NHEAD + h];
    const u8* hbase = ht8 + l16 * 16;    // this lane's 16B slice of each row

    f32x2 acc2[8];
    #pragma unroll
    for (int i = 0; i < 8; ++i) acc2[i] = (f32x2){0.f, 0.f};
    float wsum = 0.f;

    const int p0 = rowptr[dst], p1 = rowptr[dst + 1];
    const int nt = (p1 - p0 + 7) >> 3;   // uniform trips (8 edges per trip)

    float asA = -1e30f, asB = -1e30f;
    uint4 hvA = make_uint4(0u, 0u, 0u, 0u), hvB = make_uint4(0u, 0u, 0u, 0u);
    int e = p0 + q;                      // this quarter's edges: stride 4
    if (e < p1) {
        int s = (int)csr_src[e];
        asA = asrc[s * NHEAD + h];
        hvA = *(const uint4*)(hbase + ((size_t)s << 8));
    }
    if (e + 4 < p1) {
        int s = (int)csr_src[e + 4];
        asB = asrc[s * NHEAD + h];
        hvB = *(const uint4*)(hbase + ((size_t)s << 8));
    }

    for (int it = 0; it < nt; ++it) {
        float aA = asA; uint4 hA = hvA;
        float aB = asB; uint4 hB = hvB;
        asA = -1e30f; asB = -1e30f;
        if (e + 8 < p1) {                 // prefetch next trip (predicated)
            int s = (int)csr_src[e + 8];
            asA = asrc[s * NHEAD + h];
            hvA = *(const uint4*)(hbase + ((size_t)s << 8));
        }
        if (e + 12 < p1) {
            int s = (int)csr_src[e + 12];
            asB = asrc[s * NHEAD + h];
            hvB = *(const uint4*)(hbase + ((size_t)s << 8));
        }
        {   // consume A (edge e); invalid slots: w==0, finite hv -> no-op
            float x = aA + ad_own;
            x = x > 0.f ? x : NEG_SLOPE * x;
            float w = __expf(x);
            wsum += w;
            f32x2 w2; w2.x = w; w2.y = w;
            acc2[0] = __builtin_elementwise_fma(w2, __builtin_amdgcn_cvt_pk_f32_fp8(hA.x, false), acc2[0]);
            acc2[1] = __builtin_elementwise_fma(w2, __builtin_amdgcn_cvt_pk_f32_fp8(hA.x, true ), acc2[1]);
            acc2[2] = __builtin_elementwise_fma(w2, __builtin_amdgcn_cvt_pk_f32_fp8(hA.y, false), acc2[2]);
            acc2[3] = __builtin_elementwise_fma(w2, __builtin_amdgcn_cvt_pk_f32_fp8(hA.y, true ), acc2[3]);
            acc2[4] = __builtin_elementwise_fma(w2, __builtin_amdgcn_cvt_pk_f32_fp8(hA.z, false), acc2[4]);
            acc2[5] = __builtin_elementwise_fma(w2, __builtin_amdgcn_cvt_pk_f32_fp8(hA.z, true ), acc2[5]);
            acc2[6] = __builtin_elementwise_fma(w2, __builtin_amdgcn_cvt_pk_f32_fp8(hA.w, false), acc2[6]);
            acc2[7] = __builtin_elementwise_fma(w2, __builtin_amdgcn_cvt_pk_f32_fp8(hA.w, true ), acc2[7]);
        }
        {   // consume B (edge e+4)
            float x = aB + ad_own;
            x = x > 0.f ? x : NEG_SLOPE * x;
            float w = __expf(x);
            wsum += w;
            f32x2 w2; w2.x = w; w2.y = w;
            acc2[0] = __builtin_elementwise_fma(w2, __builtin_amdgcn_cvt_pk_f32_fp8(hB.x, false), acc2[0]);
            acc2[1] = __builtin_elementwise_fma(w2, __builtin_amdgcn_cvt_pk_f32_fp8(hB.x, true ), acc2[1]);
            acc2[2] = __builtin_elementwise_fma(w2, __builtin_amdgcn_cvt_pk_f32_fp8(hB.y, false), acc2[2]);
            acc2[3] = __builtin_elementwise_fma(w2, __builtin_amdgcn_cvt_pk_f32_fp8(hB.y, true ), acc2[3]);
            acc2[4] = __builtin_elementwise_fma(w2, __builtin_amdgcn_cvt_pk_f32_fp8(hB.z, false), acc2[4]);
            acc2[5] = __builtin_elementwise_fma(w2, __builtin_amdgcn_cvt_pk_f32_fp8(hB.z, true ), acc2[5]);
            acc2[6] = __builtin_elementwise_fma(w2, __builtin_amdgcn_cvt_pk_f32_fp8(hB.w, false), acc2[6]);
            acc2[7] = __builtin_elementwise_fma(w2, __builtin_amdgcn_cvt_pk_f32_fp8(hB.w, true ), acc2[7]);
        }
        e += 8;
    }

    // ---- fold the four quarters (same (h,chblk), disjoint edges) ----
    #pragma unroll
    for (int i = 0; i < 8; ++i) {
        acc2[i].x += __shfl_xor(acc2[i].x, 16, 64);
        acc2[i].y += __shfl_xor(acc2[i].y, 16, 64);
        acc2[i].x += __shfl_xor(acc2[i].x, 32, 64);
        acc2[i].y += __shfl_xor(acc2[i].y, 32, 64);
    }
    wsum += __shfl_xor(wsum, 16, 64);
    wsum += __shfl_xor(wsum, 32, 64);

    // ---- per-head softmax normalize (v_pk_mul) ----
    float winv = 1.0f / wsum;
    f32x2 winv2; winv2.x = winv; winv2.y = winv;
    #pragma unroll
    for (int i = 0; i < 8; ++i) acc2[i] *= winv2;

    // ---- sum over heads: lane = 2h + blk, fold bits 1..3 ----
    #pragma unroll
    for (int i = 0; i < 8; ++i) {
        acc2[i].x += __shfl_xor(acc2[i].x, 2, 64);
        acc2[i].y += __shfl_xor(acc2[i].y, 2, 64);
        acc2[i].x += __shfl_xor(acc2[i].x, 4, 64);
        acc2[i].y += __shfl_xor(acc2[i].y, 4, 64);
        acc2[i].x += __shfl_xor(acc2[i].x, 8, 64);
        acc2[i].y += __shfl_xor(acc2[i].y, 8, 64);
    }

    // ---- lane 0: channels 0..15, lane 1: channels 16..31 ----
    if (lane < 2) {
        const int c0 = lane * 16;
        const float4* bp4 = (const float4*)(b + c0);
        float4 b0 = bp4[0], b1 = bp4[1], b2 = bp4[2], b3 = bp4[3];
        float bb[16] = {b0.x, b0.y, b0.z, b0.w, b1.x, b1.y, b1.z, b1.w,
                        b2.x, b2.y, b2.z, b2.w, b3.x, b3.y, b3.z, b3.w};
        u32 d[8];
        #pragma unroll
        for (int i = 0; i < 8; ++i) {
            float v0 = acc2[i].x * 0.125f + bb[2 * i];
            float v1 = acc2[i].y * 0.125f + bb[2 * i + 1];
            v0 = v0 > 0.f ? v0 : (__expf(v0) - 1.f);
            v1 = v1 > 0.f ? v1 : (__expf(v1) - 1.f);
            d[i] = (u32)f2bf(v0) | ((u32)f2bf(v1) << 16);
        }
        uint4* op = (uint4*)(out + (size_t)dst * CH + c0);
        op[0] = make_uint4(d[0], d[1], d[2], d[3]);
        op[1] = make_uint4(d[4], d[5], d[6], d[7]);
    }
}

// ================= output head: 4 nodes/block (1 wave each), log_softmax
__global__ __launch_bounds__(256) void out_kernel(const u16* __restrict__ hf,
        const float* __restrict__ Wo, const float* __restrict__ bo,
        float* __restrict__ out) {
    const int wave = threadIdx.x >> 6;
    const int lane = threadIdx.x & 63;
    const int n    = blockIdx.x * 4 + wave;
    __shared__ float hs[4][CH];
    if (n < N_NODES && lane < CH) hs[wave][lane] = bflo((u32)hf[n * CH + lane]);
    __syncthreads();
    if (n >= N_NODES) return;
    float logit = -INFINITY;
    if (lane < OUT_C) {
        float a = bo[lane];
        #pragma unroll
        for (int k = 0; k < CH; ++k) a += hs[wave][k] * Wo[k * OUT_C + lane];
        logit = a;
    }
    float m = logit;
    #pragma unroll
    for (int off = 32; off; off >>= 1) m = fmaxf(m, __shfl_xor(m, off, 64));
    float ex = (lane < OUT_C) ? __expf(logit - m) : 0.f;
    float ssum = ex;
    #pragma unroll
    for (int off = 32; off; off >>= 1) ssum += __shfl_xor(ssum, off, 64);
    if (lane < OUT_C) out[(size_t)n * OUT_C + lane] = logit - m - __logf(ssum);
}

extern "C" void kernel_launch(void* const* d_in, const int* in_sizes, int n_in,
                              void* d_out, int out_size, void* d_ws, size_t ws_size,
                              hipStream_t stream) {
    const float* x      = (const float*)d_in[0];
    const int*   ei     = (const int*)  d_in[1];
    const float* W1     = (const float*)d_in[2];
    const float* a_src1 = (const float*)d_in[3];
    const float* a_dst1 = (const float*)d_in[4];
    const float* b1     = (const float*)d_in[5];
    const float* W2     = (const float*)d_in[6];
    const float* a_src2 = (const float*)d_in[7];
    const float* a_dst2 = (const float*)d_in[8];
    const float* b2     = (const float*)d_in[9];
    const float* Wo     = (const float*)d_in[10];
    const float* bo     = (const float*)d_in[11];
    float* out = (float*)d_out;

    // workspace carve-up (256B-aligned)
    char* ws = (char*)d_ws;
    size_t off = 0;
    auto carve = [&](size_t bytes) { char* p = ws + off; off += (bytes + 255) & ~(size_t)255; return p; };
    u8*    ht8     = (u8*)   carve((size_t)N_NODES * HC);          // 12.8 MB (fp8, head-major)
    u16*   Wt      = (u16*)  carve((size_t)HC * F_IN * 2);         // 128 KB (bf16 W1^T)
    u16*   W2t     = (u16*)  carve((size_t)HC * CH * 2);           // 16 KB (bf16 W2^T)
    float* asrc    = (float*)carve((size_t)N_NODES * NHEAD * 4);   // 1.6 MB
    float* adst    = (float*)carve((size_t)N_NODES * NHEAD * 4);
    u16*   hmid    = (u16*)  carve((size_t)N_PAD * CH * 2);        // 3.2 MB (bf16)
    u16*   hout    = (u16*)  carve((size_t)N_NODES * CH * 2);      // 3.2 MB (bf16)
    int*   deg     = (int*)  carve((size_t)N_NODES * 4);
    int*   rowptr  = (int*)  carve((size_t)(N_NODES + 1) * 4);
    int*   cursor  = (int*)  carve((size_t)N_NODES * 4);
    u16*   csr_src = (u16*)  carve((size_t)E_TOT * 2);             // 1.7 MB (u16)
    int*   partials= (int*)  carve((size_t)SCAN_BLOCKS * 4);

    const int g_cvt   = G_WCVT + G_WCVT2;                    // 288
    const int g_bin   = G_BINCH * NRANGE;                    // 3328
    const int g_gemm  = (N_NODES + 31) / 32;                 // 1563
    const int g_node  = (N_NODES + 255) / 256;               // 196
    const int g_attn  = (N_NODES * 64 + 255) / 256;          // 12500 (wave/dst)
    const int g_out   = (N_NODES + 3) / 4;                   // 12500

    // ---------- prep + CSR build (XCD-affine binned deg/scatter) ----------
    (void)hipMemsetAsync(deg, 0, (size_t)N_NODES * 4, stream);
    cvt_kernel<<<g_cvt, 256, 0, stream>>>(W1, Wt, W2, W2t);
    deg_kernel<<<g_bin, 256, 0, stream>>>(ei, deg);
    scan1_kernel<<<SCAN_BLOCKS, 256, 0, stream>>>(deg, rowptr, partials);
    scan2_kernel<<<1, 256, 0, stream>>>(partials);
    scan3_kernel<<<SCAN_BLOCKS, 256, 0, stream>>>(rowptr, cursor, partials);
    scatter_kernel<<<g_bin, 256, 0, stream>>>(ei, cursor, csr_src);

    // ---------- layer 1 ----------
    gemm1_mfma<<<g_gemm, 256, 0, stream>>>(x, Wt, ht8);
    alpha_t_kernel<<<g_node, 256, 0, stream>>>(ht8, a_src1, a_dst1, asrc, adst);
    attn_kernel<<<g_attn, 256, 0, stream>>>(rowptr, csr_src, asrc, adst, ht8, b1, hmid);

    // ---------- layer 2 ----------
    gemm2_mfma<<<g_gemm, 256, 0, stream>>>(hmid, W2t, ht8);
    alpha_t_kernel<<<g_node, 256, 0, stream>>>(ht8, a_src2, a_dst2, asrc, adst);
    attn_kernel<<<g_attn, 256, 0, stream>>>(rowptr, csr_src, asrc, adst, ht8, b2, hout);

    // ---------- output head ----------
    out_kernel<<<g_out, 256, 0, stream>>>(hout, Wo, bo, out);
}

// Round 5
// 380.700 us; speedup vs baseline: 1.0190x; 1.0190x over previous
//
#include <hip/hip_runtime.h>
#include <math.h>

#define N_NODES 50000
#define N_PAD   50016                 // padded to 32-row gemm tiles
#define N_EDGES 800000
#define E_TOT   (N_EDGES + N_NODES)   // edges + self-loops = 850000
#define F_IN    256
#define NHEAD   8
#define CH      32
#define HC      256                   // NHEAD*CH
#define OUT_C   40
#define NEG_SLOPE 0.2f
#define SCAN_BLOCKS ((N_NODES + 255) / 256)   // 196
#define G_WCVT  ((HC * F_IN + 255) / 256)            // 256
#define G_WCVT2 ((HC * CH + 255) / 256)              // 32
#define NRANGE  8                     // XCD count: dst-range affinity bins
#define RANGE_SZ (N_NODES / NRANGE)   // 6250
#define BIN_CHUNK 2048
#define G_BINCH ((E_TOT + BIN_CHUNK - 1) / BIN_CHUNK)   // 416
#define G_BIN   (G_BINCH * NRANGE)                      // 3328

typedef unsigned short u16;
typedef unsigned int   u32;
typedef unsigned char  u8;
typedef __attribute__((ext_vector_type(8))) short bf16x8;   // 4 VGPRs
typedef __attribute__((ext_vector_type(4))) float f32x4;
typedef __attribute__((ext_vector_type(2))) float f32x2;

__device__ __forceinline__ u16 f2bf(float f) {
    union { u32 u; float f; } x; x.f = f;
    u32 u = x.u;
    return (u16)((u + 0x7fffu + ((u >> 16) & 1u)) >> 16);   // round-nearest-even
}
__device__ __forceinline__ float bflo(u32 v) {
    union { u32 u; float f; } x; x.u = v << 16; return x.f;
}
// fp8 e4m3 encode (1 byte) / packed decode (2 floats per op) — gfx950 native
__device__ __forceinline__ u8 f2fp8(float f) {
    return (u8)(__builtin_amdgcn_cvt_pk_fp8_f32(f, f, 0, false) & 0xff);
}

// ht8 is fp8 e4m3 in NATURAL (head-major) layout: ht8[node*256 + h*32 + c].
// gemm stores are identity; in attn a 16-lane quarter reads one row as uint4.
// NOTE: f2fp8 of finite inputs saturates (never emits NaN bytes) — attn's
// stale-prefetch-register trick relies on decoded fp8 always being finite.

// ===== fused prep: binned deg atomics + W1->bf16^T + W2->bf16^T (one launch)
__global__ __launch_bounds__(256) void cvt_kernel(const float* __restrict__ W1,
        u16* __restrict__ Wt, const float* __restrict__ W2, u16* __restrict__ W2t,
        const int* __restrict__ ei, int* __restrict__ deg) {
    int b = blockIdx.x;
    if (b < G_BIN) {                  // XCD-affine binned degree count
        const int r  = b & (NRANGE - 1);
        const int ch = b >> 3;
        const int lo = r * RANGE_SZ, hi = lo + RANGE_SZ;
        int j0 = ch * BIN_CHUNK + threadIdx.x;
        #pragma unroll
        for (int i = 0; i < BIN_CHUNK / 256; ++i) {
            int j = j0 + i * 256;
            if (j < E_TOT) {
                int d = (j < N_EDGES) ? ei[N_EDGES + j] : (j - N_EDGES);
                if (d >= lo && d < hi) atomicAdd(&deg[d], 1);
            }
        }
    } else if (b < G_BIN + G_WCVT) {
        int t = (b - G_BIN) * 256 + threadIdx.x;     // 65536 total
        int n = t & 255, k = t >> 8;                 // coalesced reads
        Wt[(size_t)n * F_IN + k] = f2bf(W1[(size_t)k * HC + n]);
    } else {
        int t = (b - G_BIN - G_WCVT) * 256 + threadIdx.x;  // 8192
        if (t >= HC * CH) return;
        int n = t & 255, k = t >> 8;
        W2t[(size_t)n * CH + k] = f2bf(W2[(size_t)k * HC + n]);
    }
}

// ===== shared GEMM epilogue: fp8 ht8 store + FUSED alpha (per-row per-head
// dot with a_src/a_dst). Wave covers heads hA=nb>>5 (n=0,1) and hA+1 (n=2,3);
// channel c = n*16 + l16. Quad-local 16-lane xor-reduce; l16==0 stores.
__device__ __forceinline__ void gemm_epilogue(f32x4 acc[2][4], int row0, int quad,
        int l16, int nb, const float* __restrict__ a_src,
        const float* __restrict__ a_dst, u8* __restrict__ ht8,
        float* __restrict__ asrc, float* __restrict__ adst) {
    #pragma unroll
    for (int m = 0; m < 2; ++m) {
        #pragma unroll
        for (int r = 0; r < 4; ++r) {
            int row = row0 + m * 16 + quad * 4 + r;
            if (row < N_NODES) {
                u8* hr = ht8 + (size_t)row * HC;
                #pragma unroll
                for (int n = 0; n < 4; ++n)
                    hr[nb + n * 16 + l16] = f2fp8(acc[m][n][r]);
            }
        }
    }
    const int hA = nb >> 5;
    const float sA0 = a_src[hA * 32 + l16],       sA1 = a_src[hA * 32 + 16 + l16];
    const float sB0 = a_src[(hA + 1) * 32 + l16], sB1 = a_src[(hA + 1) * 32 + 16 + l16];
    const float dA0 = a_dst[hA * 32 + l16],       dA1 = a_dst[hA * 32 + 16 + l16];
    const float dB0 = a_dst[(hA + 1) * 32 + l16], dB1 = a_dst[(hA + 1) * 32 + 16 + l16];
    #pragma unroll
    for (int m = 0; m < 2; ++m) {
        #pragma unroll
        for (int r = 0; r < 4; ++r) {
            float pa = acc[m][0][r] * sA0 + acc[m][1][r] * sA1;
            float pb = acc[m][2][r] * sB0 + acc[m][3][r] * sB1;
            float qa = acc[m][0][r] * dA0 + acc[m][1][r] * dA1;
            float qb = acc[m][2][r] * dB0 + acc[m][3][r] * dB1;
            #pragma unroll
            for (int off = 1; off < 16; off <<= 1) {
                pa += __shfl_xor(pa, off, 64);
                pb += __shfl_xor(pb, off, 64);
                qa += __shfl_xor(qa, off, 64);
                qb += __shfl_xor(qb, off, 64);
            }
            int row = row0 + m * 16 + quad * 4 + r;
            if (l16 == 0 && row < N_NODES) {
                asrc[row * NHEAD + hA]     = pa;
                asrc[row * NHEAD + hA + 1] = pb;
                adst[row * NHEAD + hA]     = qa;
                adst[row * NHEAD + hA + 1] = qb;
            }
        }
    }
}

// ================= GEMM1: ht8 = fp8(x @ W1) + fused alpha, LDS-staged A.
// r20: r19's direct fp32 gather was latency-bound (60us, all pipes idle).
// Now: block coalesced-loads its 32x256 fp32 x-tile (contiguous 32KB),
// packs bf16 into 16KB LDS with XOR swizzle (G4: byte ^= (row&7)<<4 — the
// 512B-row-stride / 16-lanes-same-column case), one barrier, MFMA from LDS.
__global__ __launch_bounds__(256) void gemm1_mfma(const float* __restrict__ x,
        const u16* __restrict__ Wt, const float* __restrict__ a_src,
        const float* __restrict__ a_dst, u8* __restrict__ ht8,
        float* __restrict__ asrc, float* __restrict__ adst) {
    __shared__ u16 As[32 * 256];          // 16 KB bf16, swizzled
    const int row0 = blockIdx.x * 32;
    const int t    = threadIdx.x;

    {   // stage: 8 threads per row, float4-contiguous per wave
        const int r   = t >> 3;                       // 0..31
        const int sub = t & 7;
        const int gr  = min(row0 + r, N_NODES - 1);   // clamp pad rows
        const float4* xr = (const float4*)(x + (size_t)gr * F_IN);
        const int sw = (r & 7) << 4;
        char* Ar = (char*)As + r * 512;
        #pragma unroll
        for (int i = 0; i < 8; ++i) {
            int f4 = i * 8 + sub;                     // float4 idx 0..63
            float4 v = xr[f4];
            u32 lo = (u32)f2bf(v.x) | ((u32)f2bf(v.y) << 16);
            u32 hi = (u32)f2bf(v.z) | ((u32)f2bf(v.w) << 16);
            *(uint2*)(Ar + ((f4 * 8) ^ sw)) = make_uint2(lo, hi);
        }
    }
    __syncthreads();

    const int wave = t >> 6;
    const int lane = t & 63;
    const int l16  = lane & 15;
    const int quad = lane >> 4;
    const int nb   = wave * 64;
    const int swr  = (l16 & 7) << 4;
    const char* Ab = (const char*)As;

    f32x4 acc[2][4];
    #pragma unroll
    for (int m = 0; m < 2; ++m)
        #pragma unroll
        for (int n = 0; n < 4; ++n) acc[m][n] = (f32x4){0.f, 0.f, 0.f, 0.f};

    const u16* bp = Wt + (size_t)(nb + l16) * F_IN;   // N-tile stride 16*F_IN

    #pragma unroll 1
    for (int k0 = 0; k0 < F_IN; k0 += 32) {
        const int ko = k0 + quad * 8;
        bf16x8 a0 = *(const bf16x8*)(Ab + l16 * 512 + ((ko * 2) ^ swr));
        bf16x8 a1 = *(const bf16x8*)(Ab + (16 + l16) * 512 + ((ko * 2) ^ swr));
        bf16x8 b0 = *(const bf16x8*)(bp + 0 * 16 * F_IN + ko);
        bf16x8 b1 = *(const bf16x8*)(bp + 1 * 16 * F_IN + ko);
        bf16x8 b2 = *(const bf16x8*)(bp + 2 * 16 * F_IN + ko);
        bf16x8 b3 = *(const bf16x8*)(bp + 3 * 16 * F_IN + ko);
        acc[0][0] = __builtin_amdgcn_mfma_f32_16x16x32_bf16(a0, b0, acc[0][0], 0, 0, 0);
        acc[0][1] = __builtin_amdgcn_mfma_f32_16x16x32_bf16(a0, b1, acc[0][1], 0, 0, 0);
        acc[0][2] = __builtin_amdgcn_mfma_f32_16x16x32_bf16(a0, b2, acc[0][2], 0, 0, 0);
        acc[0][3] = __builtin_amdgcn_mfma_f32_16x16x32_bf16(a0, b3, acc[0][3], 0, 0, 0);
        acc[1][0] = __builtin_amdgcn_mfma_f32_16x16x32_bf16(a1, b0, acc[1][0], 0, 0, 0);
        acc[1][1] = __builtin_amdgcn_mfma_f32_16x16x32_bf16(a1, b1, acc[1][1], 0, 0, 0);
        acc[1][2] = __builtin_amdgcn_mfma_f32_16x16x32_bf16(a1, b2, acc[1][2], 0, 0, 0);
        acc[1][3] = __builtin_amdgcn_mfma_f32_16x16x32_bf16(a1, b3, acc[1][3], 0, 0, 0);
    }
    gemm_epilogue(acc, row0, quad, l16, nb, a_src, a_dst, ht8, asrc, adst);
}

// ================= GEMM2: ht8 = fp8(hmb @ W2) + fused alpha, K=32 one step
__global__ __launch_bounds__(256) void gemm2_mfma(const u16* __restrict__ hmb,
        const u16* __restrict__ W2t, const float* __restrict__ a_src,
        const float* __restrict__ a_dst, u8* __restrict__ ht8,
        float* __restrict__ asrc, float* __restrict__ adst) {
    const int row0 = blockIdx.x * 32;
    const int t    = threadIdx.x;
    const int wave = t >> 6;
    const int lane = t & 63;
    const int l16  = lane & 15;
    const int quad = lane >> 4;
    const int nb   = wave * 64;
    const int ko   = quad * 8;

    const u16* a0p = hmb + (size_t)(row0 + l16) * CH;
    const u16* a1p = a0p + 16 * CH;
    const u16* bp  = W2t + (size_t)(nb + l16) * CH;

    bf16x8 a0 = *(const bf16x8*)(a0p + ko);
    bf16x8 a1 = *(const bf16x8*)(a1p + ko);
    bf16x8 b0 = *(const bf16x8*)(bp + 0 * 16 * CH + ko);
    bf16x8 b1 = *(const bf16x8*)(bp + 1 * 16 * CH + ko);
    bf16x8 b2 = *(const bf16x8*)(bp + 2 * 16 * CH + ko);
    bf16x8 b3 = *(const bf16x8*)(bp + 3 * 16 * CH + ko);

    f32x4 z = (f32x4){0.f, 0.f, 0.f, 0.f};
    f32x4 acc[2][4];
    acc[0][0] = __builtin_amdgcn_mfma_f32_16x16x32_bf16(a0, b0, z, 0, 0, 0);
    acc[0][1] = __builtin_amdgcn_mfma_f32_16x16x32_bf16(a0, b1, z, 0, 0, 0);
    acc[0][2] = __builtin_amdgcn_mfma_f32_16x16x32_bf16(a0, b2, z, 0, 0, 0);
    acc[0][3] = __builtin_amdgcn_mfma_f32_16x16x32_bf16(a0, b3, z, 0, 0, 0);
    acc[1][0] = __builtin_amdgcn_mfma_f32_16x16x32_bf16(a1, b0, z, 0, 0, 0);
    acc[1][1] = __builtin_amdgcn_mfma_f32_16x16x32_bf16(a1, b1, z, 0, 0, 0);
    acc[1][2] = __builtin_amdgcn_mfma_f32_16x16x32_bf16(a1, b2, z, 0, 0, 0);
    acc[1][3] = __builtin_amdgcn_mfma_f32_16x16x32_bf16(a1, b3, z, 0, 0, 0);

    gemm_epilogue(acc, row0, quad, l16, nb, a_src, a_dst, ht8, asrc, adst);
}

// ================= CSR build =================
__device__ __forceinline__ int wave_incl_scan(int v, int lane) {
    #pragma unroll
    for (int d = 1; d < 64; d <<= 1) {
        int u = __shfl_up(v, d, 64);
        if (lane >= d) v += u;
    }
    return v;
}

__global__ __launch_bounds__(256) void scan1_kernel(const int* __restrict__ deg,
        int* __restrict__ rowptr, int* __restrict__ partials) {
    const int t    = blockIdx.x * 256 + threadIdx.x;
    const int lane = threadIdx.x & 63;
    const int wid  = threadIdx.x >> 6;
    int v = (t < N_NODES) ? deg[t] : 0;
    int inc = wave_incl_scan(v, lane);
    __shared__ int wtot[4];
    if (lane == 63) wtot[wid] = inc;
    __syncthreads();
    int woff = 0;
    #pragma unroll
    for (int i = 0; i < 4; ++i) woff += (i < wid) ? wtot[i] : 0;
    if (t < N_NODES) rowptr[t] = inc - v + woff;      // block-local exclusive
    if (threadIdx.x == 255) partials[blockIdx.x] = woff + inc;  // block total
}

__global__ __launch_bounds__(256) void scan2_kernel(int* __restrict__ partials) {
    const int t    = threadIdx.x;
    const int lane = t & 63;
    const int wid  = t >> 6;
    int v = (t < SCAN_BLOCKS) ? partials[t] : 0;
    int inc = wave_incl_scan(v, lane);
    __shared__ int wtot[4];
    if (lane == 63) wtot[wid] = inc;
    __syncthreads();
    int woff = 0;
    #pragma unroll
    for (int i = 0; i < 4; ++i) woff += (i < wid) ? wtot[i] : 0;
    __syncthreads();
    if (t < SCAN_BLOCKS) partials[t] = inc - v + woff;
}

__global__ __launch_bounds__(256) void scan3_kernel(int* __restrict__ rowptr,
        int* __restrict__ cursor, const int* __restrict__ partials) {
    const int t = blockIdx.x * 256 + threadIdx.x;
    if (t < N_NODES) {
        int v = rowptr[t] + partials[blockIdx.x];
        rowptr[t] = v;
        cursor[t] = v;
    } else if (t == N_NODES) {
        rowptr[N_NODES] = E_TOT;
    }
}

// XCD-affine binned scatter (r19) + u16 payload (r18).
__global__ __launch_bounds__(256) void scatter_kernel(const int* __restrict__ ei,
        int* __restrict__ cursor, u16* __restrict__ csr_src) {
    const int r  = blockIdx.x & (NRANGE - 1);
    const int ch = blockIdx.x >> 3;
    const int lo = r * RANGE_SZ, hi = lo + RANGE_SZ;
    int j0 = ch * BIN_CHUNK + threadIdx.x;
    #pragma unroll
    for (int i = 0; i < BIN_CHUNK / 256; ++i) {
        int j = j0 + i * 256;
        if (j < E_TOT) {
            int d = (j < N_EDGES) ? ei[N_EDGES + j] : (j - N_EDGES);
            if (d >= lo && d < hi) {
                int s = (j < N_EDGES) ? ei[j] : d;
                int pos = atomicAdd(&cursor[d], 1);
                csr_src[pos] = (u16)s;
            }
        }
    }
}

// ================= fused attention: one WAVE per dst node, QUARTER per edge.
// r18 loop kept (uniform trips, pk_fma, u16 csr). r20: FINAL=true fuses the
// output head (Wo matvec + log_softmax) into layer-2's epilogue — the extra
// ~100 VALU/shfl ops hide under the gather stalls; kills out_kernel + hout.
template<bool FINAL>
__global__ __launch_bounds__(256) void attn_kernel(const int* __restrict__ rowptr,
        const u16* __restrict__ csr_src, const float* __restrict__ asrc,
        const float* __restrict__ adst, const u8* __restrict__ ht8,
        const float* __restrict__ b, u16* __restrict__ out_mid,
        const float* __restrict__ Wo, const float* __restrict__ bo,
        float* __restrict__ out_final) {
    const int wid = (blockIdx.x * 256 + threadIdx.x) >> 6;   // dst node
    if (wid >= N_NODES) return;
    const int dst  = wid;
    const int lane = threadIdx.x & 63;
    const int q    = lane >> 4;          // quarter -> edge offset
    const int l16  = lane & 15;
    const int h    = l16 >> 1;           // owned head
    const float ad_own = adst[dst * NHEAD + h];
    const u8* hbase = ht8 + l16 * 16;    // this lane's 16B slice of each row

    f32x2 acc2[8];
    #pragma unroll
    for (int i = 0; i < 8; ++i) acc2[i] = (f32x2){0.f, 0.f};
    float wsum = 0.f;

    const int p0 = rowptr[dst], p1 = rowptr[dst + 1];
    const int nt = (p1 - p0 + 7) >> 3;   // uniform trips (8 edges per trip)

    float asA = -1e30f, asB = -1e30f;
    uint4 hvA = make_uint4(0u, 0u, 0u, 0u), hvB = make_uint4(0u, 0u, 0u, 0u);
    int e = p0 + q;                      // this quarter's edges: stride 4
    if (e < p1) {
        int s = (int)csr_src[e];
        asA = asrc[s * NHEAD + h];
        hvA = *(const uint4*)(hbase + ((size_t)s << 8));
    }
    if (e + 4 < p1) {
        int s = (int)csr_src[e + 4];
        asB = asrc[s * NHEAD + h];
        hvB = *(const uint4*)(hbase + ((size_t)s << 8));
    }

    for (int it = 0; it < nt; ++it) {
        float aA = asA; uint4 hA = hvA;
        float aB = asB; uint4 hB = hvB;
        asA = -1e30f; asB = -1e30f;
        if (e + 8 < p1) {                 // prefetch next trip (predicated)
            int s = (int)csr_src[e + 8];
            asA = asrc[s * NHEAD + h];
            hvA = *(const uint4*)(hbase + ((size_t)s << 8));
        }
        if (e + 12 < p1) {
            int s = (int)csr_src[e + 12];
            asB = asrc[s * NHEAD + h];
            hvB = *(const uint4*)(hbase + ((size_t)s << 8));
        }
        {   // consume A (edge e); invalid slots: w==0, finite hv -> no-op
            float x = aA + ad_own;
            x = x > 0.f ? x : NEG_SLOPE * x;
            float w = __expf(x);
            wsum += w;
            f32x2 w2; w2.x = w; w2.y = w;
            acc2[0] = __builtin_elementwise_fma(w2, __builtin_amdgcn_cvt_pk_f32_fp8(hA.x, false), acc2[0]);
            acc2[1] = __builtin_elementwise_fma(w2, __builtin_amdgcn_cvt_pk_f32_fp8(hA.x, true ), acc2[1]);
            acc2[2] = __builtin_elementwise_fma(w2, __builtin_amdgcn_cvt_pk_f32_fp8(hA.y, false), acc2[2]);
            acc2[3] = __builtin_elementwise_fma(w2, __builtin_amdgcn_cvt_pk_f32_fp8(hA.y, true ), acc2[3]);
            acc2[4] = __builtin_elementwise_fma(w2, __builtin_amdgcn_cvt_pk_f32_fp8(hA.z, false), acc2[4]);
            acc2[5] = __builtin_elementwise_fma(w2, __builtin_amdgcn_cvt_pk_f32_fp8(hA.z, true ), acc2[5]);
            acc2[6] = __builtin_elementwise_fma(w2, __builtin_amdgcn_cvt_pk_f32_fp8(hA.w, false), acc2[6]);
            acc2[7] = __builtin_elementwise_fma(w2, __builtin_amdgcn_cvt_pk_f32_fp8(hA.w, true ), acc2[7]);
        }
        {   // consume B (edge e+4)
            float x = aB + ad_own;
            x = x > 0.f ? x : NEG_SLOPE * x;
            float w = __expf(x);
            wsum += w;
            f32x2 w2; w2.x = w; w2.y = w;
            acc2[0] = __builtin_elementwise_fma(w2, __builtin_amdgcn_cvt_pk_f32_fp8(hB.x, false), acc2[0]);
            acc2[1] = __builtin_elementwise_fma(w2, __builtin_amdgcn_cvt_pk_f32_fp8(hB.x, true ), acc2[1]);
            acc2[2] = __builtin_elementwise_fma(w2, __builtin_amdgcn_cvt_pk_f32_fp8(hB.y, false), acc2[2]);
            acc2[3] = __builtin_elementwise_fma(w2, __builtin_amdgcn_cvt_pk_f32_fp8(hB.y, true ), acc2[3]);
            acc2[4] = __builtin_elementwise_fma(w2, __builtin_amdgcn_cvt_pk_f32_fp8(hB.z, false), acc2[4]);
            acc2[5] = __builtin_elementwise_fma(w2, __builtin_amdgcn_cvt_pk_f32_fp8(hB.z, true ), acc2[5]);
            acc2[6] = __builtin_elementwise_fma(w2, __builtin_amdgcn_cvt_pk_f32_fp8(hB.w, false), acc2[6]);
            acc2[7] = __builtin_elementwise_fma(w2, __builtin_amdgcn_cvt_pk_f32_fp8(hB.w, true ), acc2[7]);
        }
        e += 8;
    }

    // ---- fold the four quarters (same (h,chblk), disjoint edges) ----
    #pragma unroll
    for (int i = 0; i < 8; ++i) {
        acc2[i].x += __shfl_xor(acc2[i].x, 16, 64);
        acc2[i].y += __shfl_xor(acc2[i].y, 16, 64);
        acc2[i].x += __shfl_xor(acc2[i].x, 32, 64);
        acc2[i].y += __shfl_xor(acc2[i].y, 32, 64);
    }
    wsum += __shfl_xor(wsum, 16, 64);
    wsum += __shfl_xor(wsum, 32, 64);

    // ---- per-head softmax normalize ----
    float winv = 1.0f / wsum;
    f32x2 winv2; winv2.x = winv; winv2.y = winv;
    #pragma unroll
    for (int i = 0; i < 8; ++i) acc2[i] *= winv2;

    // ---- sum over heads: fold lane bits 1..3; every lane ends with its
    // parity's 16 channels (blk = lane&1 -> channels blk*16 + 2i,2i+1) ----
    #pragma unroll
    for (int i = 0; i < 8; ++i) {
        acc2[i].x += __shfl_xor(acc2[i].x, 2, 64);
        acc2[i].y += __shfl_xor(acc2[i].y, 2, 64);
        acc2[i].x += __shfl_xor(acc2[i].x, 4, 64);
        acc2[i].y += __shfl_xor(acc2[i].y, 4, 64);
        acc2[i].x += __shfl_xor(acc2[i].x, 8, 64);
        acc2[i].y += __shfl_xor(acc2[i].y, 8, 64);
    }

    if constexpr (!FINAL) {
        // ---- lane 0: channels 0..15, lane 1: channels 16..31 (bf16) ----
        if (lane < 2) {
            const int c0 = lane * 16;
            const float4* bp4 = (const float4*)(b + c0);
            float4 b0 = bp4[0], b1 = bp4[1], b2 = bp4[2], b3 = bp4[3];
            float bb[16] = {b0.x, b0.y, b0.z, b0.w, b1.x, b1.y, b1.z, b1.w,
                            b2.x, b2.y, b2.z, b2.w, b3.x, b3.y, b3.z, b3.w};
            u32 d[8];
            #pragma unroll
            for (int i = 0; i < 8; ++i) {
                float v0 = acc2[i].x * 0.125f + bb[2 * i];
                float v1 = acc2[i].y * 0.125f + bb[2 * i + 1];
                v0 = v0 > 0.f ? v0 : (__expf(v0) - 1.f);
                v1 = v1 > 0.f ? v1 : (__expf(v1) - 1.f);
                d[i] = (u32)f2bf(v0) | ((u32)f2bf(v1) << 16);
            }
            uint4* op = (uint4*)(out_mid + (size_t)dst * CH + c0);
            op[0] = make_uint4(d[0], d[1], d[2], d[3]);
            op[1] = make_uint4(d[4], d[5], d[6], d[7]);
        }
    } else {
        // ---- fused output head: bias+ELU (all lanes), gather 32 ch via
        // shfl from lanes 0/1, 40-col matvec with Wo, log_softmax ----
        const int c0f = (lane & 1) * 16;
        const float4* bp4 = (const float4*)(b + c0f);
        float4 b0 = bp4[0], b1 = bp4[1], b2 = bp4[2], b3 = bp4[3];
        float bb[16] = {b0.x, b0.y, b0.z, b0.w, b1.x, b1.y, b1.z, b1.w,
                        b2.x, b2.y, b2.z, b2.w, b3.x, b3.y, b3.z, b3.w};
        float v[16];
        #pragma unroll
        for (int i = 0; i < 8; ++i) {
            float v0 = acc2[i].x * 0.125f + bb[2 * i];
            float v1 = acc2[i].y * 0.125f + bb[2 * i + 1];
            v[2 * i]     = v0 > 0.f ? v0 : (__expf(v0) - 1.f);
            v[2 * i + 1] = v1 > 0.f ? v1 : (__expf(v1) - 1.f);
        }
        float logit = -INFINITY;
        if (lane < OUT_C) logit = bo[lane];
        #pragma unroll
        for (int k = 0; k < 16; ++k) {
            float h0 = __shfl(v[k], 0, 64);       // channel k      (lane 0)
            float h1 = __shfl(v[k], 1, 64);       // channel 16+k   (lane 1)
            if (lane < OUT_C)
                logit += h0 * Wo[k * OUT_C + lane] + h1 * Wo[(16 + k) * OUT_C + lane];
        }
        float mx = logit;
        #pragma unroll
        for (int off = 32; off; off >>= 1) mx = fmaxf(mx, __shfl_xor(mx, off, 64));
        float ex = (lane < OUT_C) ? __expf(logit - mx) : 0.f;
        float ss = ex;
        #pragma unroll
        for (int off = 32; off; off >>= 1) ss += __shfl_xor(ss, off, 64);
        if (lane < OUT_C)
            out_final[(size_t)dst * OUT_C + lane] = logit - mx - __logf(ss);
    }
}

extern "C" void kernel_launch(void* const* d_in, const int* in_sizes, int n_in,
                              void* d_out, int out_size, void* d_ws, size_t ws_size,
                              hipStream_t stream) {
    const float* x      = (const float*)d_in[0];
    const int*   ei     = (const int*)  d_in[1];
    const float* W1     = (const float*)d_in[2];
    const float* a_src1 = (const float*)d_in[3];
    const float* a_dst1 = (const float*)d_in[4];
    const float* b1     = (const float*)d_in[5];
    const float* W2     = (const float*)d_in[6];
    const float* a_src2 = (const float*)d_in[7];
    const float* a_dst2 = (const float*)d_in[8];
    const float* b2     = (const float*)d_in[9];
    const float* Wo     = (const float*)d_in[10];
    const float* bo     = (const float*)d_in[11];
    float* out = (float*)d_out;

    // workspace carve-up (256B-aligned)
    char* ws = (char*)d_ws;
    size_t off = 0;
    auto carve = [&](size_t bytes) { char* p = ws + off; off += (bytes + 255) & ~(size_t)255; return p; };
    u8*    ht8     = (u8*)   carve((size_t)N_NODES * HC);          // 12.8 MB (fp8, head-major)
    u16*   Wt      = (u16*)  carve((size_t)HC * F_IN * 2);         // 128 KB (bf16 W1^T)
    u16*   W2t     = (u16*)  carve((size_t)HC * CH * 2);           // 16 KB (bf16 W2^T)
    float* asrc    = (float*)carve((size_t)N_NODES * NHEAD * 4);   // 1.6 MB
    float* adst    = (float*)carve((size_t)N_NODES * NHEAD * 4);
    u16*   hmid    = (u16*)  carve((size_t)N_PAD * CH * 2);        // 3.2 MB (bf16)
    int*   deg     = (int*)  carve((size_t)N_NODES * 4);
    int*   rowptr  = (int*)  carve((size_t)(N_NODES + 1) * 4);
    int*   cursor  = (int*)  carve((size_t)N_NODES * 4);
    u16*   csr_src = (u16*)  carve((size_t)E_TOT * 2);             // 1.7 MB (u16)
    int*   partials= (int*)  carve((size_t)SCAN_BLOCKS * 4);

    const int g_cvt   = G_BIN + G_WCVT + G_WCVT2;            // 3616
    const int g_gemm  = (N_NODES + 31) / 32;                 // 1563
    const int g_attn  = (N_NODES * 64 + 255) / 256;          // 12500 (wave/dst)

    // ---------- prep + CSR build ----------
    (void)hipMemsetAsync(deg, 0, (size_t)N_NODES * 4, stream);
    cvt_kernel<<<g_cvt, 256, 0, stream>>>(W1, Wt, W2, W2t, ei, deg);
    scan1_kernel<<<SCAN_BLOCKS, 256, 0, stream>>>(deg, rowptr, partials);
    scan2_kernel<<<1, 256, 0, stream>>>(partials);
    scan3_kernel<<<SCAN_BLOCKS, 256, 0, stream>>>(rowptr, cursor, partials);
    scatter_kernel<<<G_BIN, 256, 0, stream>>>(ei, cursor, csr_src);

    // ---------- layer 1 (alpha fused into gemm epilogue) ----------
    gemm1_mfma<<<g_gemm, 256, 0, stream>>>(x, Wt, a_src1, a_dst1, ht8, asrc, adst);
    attn_kernel<false><<<g_attn, 256, 0, stream>>>(rowptr, csr_src, asrc, adst,
                                                   ht8, b1, hmid, nullptr, nullptr, nullptr);

    // ---------- layer 2 (+ fused output head) ----------
    gemm2_mfma<<<g_gemm, 256, 0, stream>>>(hmid, W2t, a_src2, a_dst2, ht8, asrc, adst);
    attn_kernel<true><<<g_attn, 256, 0, stream>>>(rowptr, csr_src, asrc, adst,
                                                  ht8, b2, nullptr, Wo, bo, out);
}

// Round 6
// 360.708 us; speedup vs baseline: 1.0755x; 1.0554x over previous
//
#include <hip/hip_runtime.h>
#include <math.h>

#define N_NODES 50000
#define N_PAD   50016                 // padded to 32-row gemm tiles
#define N_EDGES 800000
#define E_TOT   (N_EDGES + N_NODES)   // edges + self-loops = 850000
#define F_IN    256
#define NHEAD   8
#define CH      32
#define HC      256                   // NHEAD*CH
#define OUT_C   40
#define NEG_SLOPE 0.2f
#define SCAN_BLOCKS ((N_NODES + 255) / 256)   // 196
#define G_WCVT  ((HC * F_IN + 255) / 256)            // 256
#define G_WCVT2 ((HC * CH + 255) / 256)              // 32
#define NRANGE  8                     // XCD count: dst-range affinity bins
#define RANGE_SZ (N_NODES / NRANGE)   // 6250
#define BIN_CHUNK 2048
#define G_BINCH ((E_TOT + BIN_CHUNK - 1) / BIN_CHUNK)   // 416
#define G_BIN   (G_BINCH * NRANGE)                      // 3328

typedef unsigned short u16;
typedef unsigned int   u32;
typedef unsigned char  u8;
typedef __attribute__((ext_vector_type(8))) short bf16x8;   // 4 VGPRs
typedef __attribute__((ext_vector_type(4))) float f32x4;
typedef __attribute__((ext_vector_type(2))) float f32x2;

__device__ __forceinline__ u16 f2bf(float f) {
    union { u32 u; float f; } x; x.f = f;
    u32 u = x.u;
    return (u16)((u + 0x7fffu + ((u >> 16) & 1u)) >> 16);   // round-nearest-even
}
__device__ __forceinline__ float bflo(u32 v) {
    union { u32 u; float f; } x; x.u = v << 16; return x.f;
}
// fp8 e4m3 encode (1 byte) / packed decode (2 floats per op) — gfx950 native
__device__ __forceinline__ u8 f2fp8(float f) {
    return (u8)(__builtin_amdgcn_cvt_pk_fp8_f32(f, f, 0, false) & 0xff);
}

// ht8 is fp8 e4m3 in NATURAL (head-major) layout: ht8[node*256 + h*32 + c].
// gemm stores are identity; in attn a 16-lane quarter reads one row as uint4.
// NOTE: f2fp8 of finite inputs saturates (never emits NaN bytes) — attn's
// stale-prefetch-register trick relies on decoded fp8 always being finite.
// r21: out-head fusion REVERTED — co-compiled template variants both spilled
// (rule #19: VGPR 28->40, +4.6MB scratch writes, attn 58->96us). attn is back
// to the exact r3 body (proven 57.8us codegen); out_kernel is standalone.

// ===== fused prep: binned deg atomics + W1->bf16^T + W2->bf16^T (one launch)
__global__ __launch_bounds__(256) void cvt_kernel(const float* __restrict__ W1,
        u16* __restrict__ Wt, const float* __restrict__ W2, u16* __restrict__ W2t,
        const int* __restrict__ ei, int* __restrict__ deg) {
    int b = blockIdx.x;
    if (b < G_BIN) {                  // XCD-affine binned degree count
        const int r  = b & (NRANGE - 1);
        const int ch = b >> 3;
        const int lo = r * RANGE_SZ, hi = lo + RANGE_SZ;
        int j0 = ch * BIN_CHUNK + threadIdx.x;
        #pragma unroll
        for (int i = 0; i < BIN_CHUNK / 256; ++i) {
            int j = j0 + i * 256;
            if (j < E_TOT) {
                int d = (j < N_EDGES) ? ei[N_EDGES + j] : (j - N_EDGES);
                if (d >= lo && d < hi) atomicAdd(&deg[d], 1);
            }
        }
    } else if (b < G_BIN + G_WCVT) {
        int t = (b - G_BIN) * 256 + threadIdx.x;     // 65536 total
        int n = t & 255, k = t >> 8;                 // coalesced reads
        Wt[(size_t)n * F_IN + k] = f2bf(W1[(size_t)k * HC + n]);
    } else {
        int t = (b - G_BIN - G_WCVT) * 256 + threadIdx.x;  // 8192
        if (t >= HC * CH) return;
        int n = t & 255, k = t >> 8;
        W2t[(size_t)n * CH + k] = f2bf(W2[(size_t)k * HC + n]);
    }
}

// ===== shared GEMM epilogue: fp8 ht8 store + FUSED alpha (per-row per-head
// dot with a_src/a_dst). Wave covers heads hA=nb>>5 (n=0,1) and hA+1 (n=2,3);
// channel c = n*16 + l16. Quad-local 16-lane xor-reduce; l16==0 stores.
__device__ __forceinline__ void gemm_epilogue(f32x4 acc[2][4], int row0, int quad,
        int l16, int nb, const float* __restrict__ a_src,
        const float* __restrict__ a_dst, u8* __restrict__ ht8,
        float* __restrict__ asrc, float* __restrict__ adst) {
    #pragma unroll
    for (int m = 0; m < 2; ++m) {
        #pragma unroll
        for (int r = 0; r < 4; ++r) {
            int row = row0 + m * 16 + quad * 4 + r;
            if (row < N_NODES) {
                u8* hr = ht8 + (size_t)row * HC;
                #pragma unroll
                for (int n = 0; n < 4; ++n)
                    hr[nb + n * 16 + l16] = f2fp8(acc[m][n][r]);
            }
        }
    }
    const int hA = nb >> 5;
    const float sA0 = a_src[hA * 32 + l16],       sA1 = a_src[hA * 32 + 16 + l16];
    const float sB0 = a_src[(hA + 1) * 32 + l16], sB1 = a_src[(hA + 1) * 32 + 16 + l16];
    const float dA0 = a_dst[hA * 32 + l16],       dA1 = a_dst[hA * 32 + 16 + l16];
    const float dB0 = a_dst[(hA + 1) * 32 + l16], dB1 = a_dst[(hA + 1) * 32 + 16 + l16];
    #pragma unroll
    for (int m = 0; m < 2; ++m) {
        #pragma unroll
        for (int r = 0; r < 4; ++r) {
            float pa = acc[m][0][r] * sA0 + acc[m][1][r] * sA1;
            float pb = acc[m][2][r] * sB0 + acc[m][3][r] * sB1;
            float qa = acc[m][0][r] * dA0 + acc[m][1][r] * dA1;
            float qb = acc[m][2][r] * dB0 + acc[m][3][r] * dB1;
            #pragma unroll
            for (int off = 1; off < 16; off <<= 1) {
                pa += __shfl_xor(pa, off, 64);
                pb += __shfl_xor(pb, off, 64);
                qa += __shfl_xor(qa, off, 64);
                qb += __shfl_xor(qb, off, 64);
            }
            int row = row0 + m * 16 + quad * 4 + r;
            if (l16 == 0 && row < N_NODES) {
                asrc[row * NHEAD + hA]     = pa;
                asrc[row * NHEAD + hA + 1] = pb;
                adst[row * NHEAD + hA]     = qa;
                adst[row * NHEAD + hA + 1] = qb;
            }
        }
    }
}

// ================= GEMM1: ht8 = fp8(x @ W1) + fused alpha, LDS-staged A.
// r20: block coalesced-loads its 32x256 fp32 x-tile (contiguous 32KB),
// packs bf16 into 16KB LDS with XOR swizzle (G4: byte ^= (row&7)<<4),
// one barrier, MFMA from LDS.
__global__ __launch_bounds__(256) void gemm1_mfma(const float* __restrict__ x,
        const u16* __restrict__ Wt, const float* __restrict__ a_src,
        const float* __restrict__ a_dst, u8* __restrict__ ht8,
        float* __restrict__ asrc, float* __restrict__ adst) {
    __shared__ u16 As[32 * 256];          // 16 KB bf16, swizzled
    const int row0 = blockIdx.x * 32;
    const int t    = threadIdx.x;

    {   // stage: 8 threads per row, float4-contiguous per wave
        const int r   = t >> 3;                       // 0..31
        const int sub = t & 7;
        const int gr  = min(row0 + r, N_NODES - 1);   // clamp pad rows
        const float4* xr = (const float4*)(x + (size_t)gr * F_IN);
        const int sw = (r & 7) << 4;
        char* Ar = (char*)As + r * 512;
        #pragma unroll
        for (int i = 0; i < 8; ++i) {
            int f4 = i * 8 + sub;                     // float4 idx 0..63
            float4 v = xr[f4];
            u32 lo = (u32)f2bf(v.x) | ((u32)f2bf(v.y) << 16);
            u32 hi = (u32)f2bf(v.z) | ((u32)f2bf(v.w) << 16);
            *(uint2*)(Ar + ((f4 * 8) ^ sw)) = make_uint2(lo, hi);
        }
    }
    __syncthreads();

    const int wave = t >> 6;
    const int lane = t & 63;
    const int l16  = lane & 15;
    const int quad = lane >> 4;
    const int nb   = wave * 64;
    const int swr  = (l16 & 7) << 4;
    const char* Ab = (const char*)As;

    f32x4 acc[2][4];
    #pragma unroll
    for (int m = 0; m < 2; ++m)
        #pragma unroll
        for (int n = 0; n < 4; ++n) acc[m][n] = (f32x4){0.f, 0.f, 0.f, 0.f};

    const u16* bp = Wt + (size_t)(nb + l16) * F_IN;   // N-tile stride 16*F_IN

    #pragma unroll 1
    for (int k0 = 0; k0 < F_IN; k0 += 32) {
        const int ko = k0 + quad * 8;
        bf16x8 a0 = *(const bf16x8*)(Ab + l16 * 512 + ((ko * 2) ^ swr));
        bf16x8 a1 = *(const bf16x8*)(Ab + (16 + l16) * 512 + ((ko * 2) ^ swr));
        bf16x8 b0 = *(const bf16x8*)(bp + 0 * 16 * F_IN + ko);
        bf16x8 b1 = *(const bf16x8*)(bp + 1 * 16 * F_IN + ko);
        bf16x8 b2 = *(const bf16x8*)(bp + 2 * 16 * F_IN + ko);
        bf16x8 b3 = *(const bf16x8*)(bp + 3 * 16 * F_IN + ko);
        acc[0][0] = __builtin_amdgcn_mfma_f32_16x16x32_bf16(a0, b0, acc[0][0], 0, 0, 0);
        acc[0][1] = __builtin_amdgcn_mfma_f32_16x16x32_bf16(a0, b1, acc[0][1], 0, 0, 0);
        acc[0][2] = __builtin_amdgcn_mfma_f32_16x16x32_bf16(a0, b2, acc[0][2], 0, 0, 0);
        acc[0][3] = __builtin_amdgcn_mfma_f32_16x16x32_bf16(a0, b3, acc[0][3], 0, 0, 0);
        acc[1][0] = __builtin_amdgcn_mfma_f32_16x16x32_bf16(a1, b0, acc[1][0], 0, 0, 0);
        acc[1][1] = __builtin_amdgcn_mfma_f32_16x16x32_bf16(a1, b1, acc[1][1], 0, 0, 0);
        acc[1][2] = __builtin_amdgcn_mfma_f32_16x16x32_bf16(a1, b2, acc[1][2], 0, 0, 0);
        acc[1][3] = __builtin_amdgcn_mfma_f32_16x16x32_bf16(a1, b3, acc[1][3], 0, 0, 0);
    }
    gemm_epilogue(acc, row0, quad, l16, nb, a_src, a_dst, ht8, asrc, adst);
}

// ================= GEMM2: ht8 = fp8(hmb @ W2) + fused alpha, K=32 one step
__global__ __launch_bounds__(256) void gemm2_mfma(const u16* __restrict__ hmb,
        const u16* __restrict__ W2t, const float* __restrict__ a_src,
        const float* __restrict__ a_dst, u8* __restrict__ ht8,
        float* __restrict__ asrc, float* __restrict__ adst) {
    const int row0 = blockIdx.x * 32;
    const int t    = threadIdx.x;
    const int wave = t >> 6;
    const int lane = t & 63;
    const int l16  = lane & 15;
    const int quad = lane >> 4;
    const int nb   = wave * 64;
    const int ko   = quad * 8;

    const u16* a0p = hmb + (size_t)(row0 + l16) * CH;
    const u16* a1p = a0p + 16 * CH;
    const u16* bp  = W2t + (size_t)(nb + l16) * CH;

    bf16x8 a0 = *(const bf16x8*)(a0p + ko);
    bf16x8 a1 = *(const bf16x8*)(a1p + ko);
    bf16x8 b0 = *(const bf16x8*)(bp + 0 * 16 * CH + ko);
    bf16x8 b1 = *(const bf16x8*)(bp + 1 * 16 * CH + ko);
    bf16x8 b2 = *(const bf16x8*)(bp + 2 * 16 * CH + ko);
    bf16x8 b3 = *(const bf16x8*)(bp + 3 * 16 * CH + ko);

    f32x4 z = (f32x4){0.f, 0.f, 0.f, 0.f};
    f32x4 acc[2][4];
    acc[0][0] = __builtin_amdgcn_mfma_f32_16x16x32_bf16(a0, b0, z, 0, 0, 0);
    acc[0][1] = __builtin_amdgcn_mfma_f32_16x16x32_bf16(a0, b1, z, 0, 0, 0);
    acc[0][2] = __builtin_amdgcn_mfma_f32_16x16x32_bf16(a0, b2, z, 0, 0, 0);
    acc[0][3] = __builtin_amdgcn_mfma_f32_16x16x32_bf16(a0, b3, z, 0, 0, 0);
    acc[1][0] = __builtin_amdgcn_mfma_f32_16x16x32_bf16(a1, b0, z, 0, 0, 0);
    acc[1][1] = __builtin_amdgcn_mfma_f32_16x16x32_bf16(a1, b1, z, 0, 0, 0);
    acc[1][2] = __builtin_amdgcn_mfma_f32_16x16x32_bf16(a1, b2, z, 0, 0, 0);
    acc[1][3] = __builtin_amdgcn_mfma_f32_16x16x32_bf16(a1, b3, z, 0, 0, 0);

    gemm_epilogue(acc, row0, quad, l16, nb, a_src, a_dst, ht8, asrc, adst);
}

// ================= CSR build =================
__device__ __forceinline__ int wave_incl_scan(int v, int lane) {
    #pragma unroll
    for (int d = 1; d < 64; d <<= 1) {
        int u = __shfl_up(v, d, 64);
        if (lane >= d) v += u;
    }
    return v;
}

__global__ __launch_bounds__(256) void scan1_kernel(const int* __restrict__ deg,
        int* __restrict__ rowptr, int* __restrict__ partials) {
    const int t    = blockIdx.x * 256 + threadIdx.x;
    const int lane = threadIdx.x & 63;
    const int wid  = threadIdx.x >> 6;
    int v = (t < N_NODES) ? deg[t] : 0;
    int inc = wave_incl_scan(v, lane);
    __shared__ int wtot[4];
    if (lane == 63) wtot[wid] = inc;
    __syncthreads();
    int woff = 0;
    #pragma unroll
    for (int i = 0; i < 4; ++i) woff += (i < wid) ? wtot[i] : 0;
    if (t < N_NODES) rowptr[t] = inc - v + woff;      // block-local exclusive
    if (threadIdx.x == 255) partials[blockIdx.x] = woff + inc;  // block total
}

__global__ __launch_bounds__(256) void scan2_kernel(int* __restrict__ partials) {
    const int t    = threadIdx.x;
    const int lane = t & 63;
    const int wid  = t >> 6;
    int v = (t < SCAN_BLOCKS) ? partials[t] : 0;
    int inc = wave_incl_scan(v, lane);
    __shared__ int wtot[4];
    if (lane == 63) wtot[wid] = inc;
    __syncthreads();
    int woff = 0;
    #pragma unroll
    for (int i = 0; i < 4; ++i) woff += (i < wid) ? wtot[i] : 0;
    __syncthreads();
    if (t < SCAN_BLOCKS) partials[t] = inc - v + woff;
}

__global__ __launch_bounds__(256) void scan3_kernel(int* __restrict__ rowptr,
        int* __restrict__ cursor, const int* __restrict__ partials) {
    const int t = blockIdx.x * 256 + threadIdx.x;
    if (t < N_NODES) {
        int v = rowptr[t] + partials[blockIdx.x];
        rowptr[t] = v;
        cursor[t] = v;
    } else if (t == N_NODES) {
        rowptr[N_NODES] = E_TOT;
    }
}

// XCD-affine binned scatter (r19) + u16 payload (r18).
__global__ __launch_bounds__(256) void scatter_kernel(const int* __restrict__ ei,
        int* __restrict__ cursor, u16* __restrict__ csr_src) {
    const int r  = blockIdx.x & (NRANGE - 1);
    const int ch = blockIdx.x >> 3;
    const int lo = r * RANGE_SZ, hi = lo + RANGE_SZ;
    int j0 = ch * BIN_CHUNK + threadIdx.x;
    #pragma unroll
    for (int i = 0; i < BIN_CHUNK / 256; ++i) {
        int j = j0 + i * 256;
        if (j < E_TOT) {
            int d = (j < N_EDGES) ? ei[N_EDGES + j] : (j - N_EDGES);
            if (d >= lo && d < hi) {
                int s = (j < N_EDGES) ? ei[j] : d;
                int pos = atomicAdd(&cursor[d], 1);
                csr_src[pos] = (u16)s;
            }
        }
    }
}

// ================= fused attention: one WAVE per dst node, QUARTER per edge.
// Exact r3 body (proven 57.8us codegen): uniform trips, pk_fma, u16 csr.
__global__ __launch_bounds__(256) void attn_kernel(const int* __restrict__ rowptr,
        const u16* __restrict__ csr_src, const float* __restrict__ asrc,
        const float* __restrict__ adst, const u8* __restrict__ ht8,
        const float* __restrict__ b, u16* __restrict__ out) {
    const int wid = (blockIdx.x * 256 + threadIdx.x) >> 6;   // dst node
    if (wid >= N_NODES) return;
    const int dst  = wid;
    const int lane = threadIdx.x & 63;
    const int q    = lane >> 4;          // quarter -> edge offset
    const int l16  = lane & 15;
    const int h    = l16 >> 1;           // owned head
    const float ad_own = adst[dst * NHEAD + h];
    const u8* hbase = ht8 + l16 * 16;    // this lane's 16B slice of each row

    f32x2 acc2[8];
    #pragma unroll
    for (int i = 0; i < 8; ++i) acc2[i] = (f32x2){0.f, 0.f};
    float wsum = 0.f;

    const int p0 = rowptr[dst], p1 = rowptr[dst + 1];
    const int nt = (p1 - p0 + 7) >> 3;   // uniform trips (8 edges per trip)

    float asA = -1e30f, asB = -1e30f;
    uint4 hvA = make_uint4(0u, 0u, 0u, 0u), hvB = make_uint4(0u, 0u, 0u, 0u);
    int e = p0 + q;                      // this quarter's edges: stride 4
    if (e < p1) {
        int s = (int)csr_src[e];
        asA = asrc[s * NHEAD + h];
        hvA = *(const uint4*)(hbase + ((size_t)s << 8));
    }
    if (e + 4 < p1) {
        int s = (int)csr_src[e + 4];
        asB = asrc[s * NHEAD + h];
        hvB = *(const uint4*)(hbase + ((size_t)s << 8));
    }

    for (int it = 0; it < nt; ++it) {
        float aA = asA; uint4 hA = hvA;
        float aB = asB; uint4 hB = hvB;
        asA = -1e30f; asB = -1e30f;
        if (e + 8 < p1) {                 // prefetch next trip (predicated)
            int s = (int)csr_src[e + 8];
            asA = asrc[s * NHEAD + h];
            hvA = *(const uint4*)(hbase + ((size_t)s << 8));
        }
        if (e + 12 < p1) {
            int s = (int)csr_src[e + 12];
            asB = asrc[s * NHEAD + h];
            hvB = *(const uint4*)(hbase + ((size_t)s << 8));
        }
        {   // consume A (edge e); invalid slots: w==0, finite hv -> no-op
            float x = aA + ad_own;
            x = x > 0.f ? x : NEG_SLOPE * x;
            float w = __expf(x);
            wsum += w;
            f32x2 w2; w2.x = w; w2.y = w;
            acc2[0] = __builtin_elementwise_fma(w2, __builtin_amdgcn_cvt_pk_f32_fp8(hA.x, false), acc2[0]);
            acc2[1] = __builtin_elementwise_fma(w2, __builtin_amdgcn_cvt_pk_f32_fp8(hA.x, true ), acc2[1]);
            acc2[2] = __builtin_elementwise_fma(w2, __builtin_amdgcn_cvt_pk_f32_fp8(hA.y, false), acc2[2]);
            acc2[3] = __builtin_elementwise_fma(w2, __builtin_amdgcn_cvt_pk_f32_fp8(hA.y, true ), acc2[3]);
            acc2[4] = __builtin_elementwise_fma(w2, __builtin_amdgcn_cvt_pk_f32_fp8(hA.z, false), acc2[4]);
            acc2[5] = __builtin_elementwise_fma(w2, __builtin_amdgcn_cvt_pk_f32_fp8(hA.z, true ), acc2[5]);
            acc2[6] = __builtin_elementwise_fma(w2, __builtin_amdgcn_cvt_pk_f32_fp8(hA.w, false), acc2[6]);
            acc2[7] = __builtin_elementwise_fma(w2, __builtin_amdgcn_cvt_pk_f32_fp8(hA.w, true ), acc2[7]);
        }
        {   // consume B (edge e+4)
            float x = aB + ad_own;
            x = x > 0.f ? x : NEG_SLOPE * x;
            float w = __expf(x);
            wsum += w;
            f32x2 w2; w2.x = w; w2.y = w;
            acc2[0] = __builtin_elementwise_fma(w2, __builtin_amdgcn_cvt_pk_f32_fp8(hB.x, false), acc2[0]);
            acc2[1] = __builtin_elementwise_fma(w2, __builtin_amdgcn_cvt_pk_f32_fp8(hB.x, true ), acc2[1]);
            acc2[2] = __builtin_elementwise_fma(w2, __builtin_amdgcn_cvt_pk_f32_fp8(hB.y, false), acc2[2]);
            acc2[3] = __builtin_elementwise_fma(w2, __builtin_amdgcn_cvt_pk_f32_fp8(hB.y, true ), acc2[3]);
            acc2[4] = __builtin_elementwise_fma(w2, __builtin_amdgcn_cvt_pk_f32_fp8(hB.z, false), acc2[4]);
            acc2[5] = __builtin_elementwise_fma(w2, __builtin_amdgcn_cvt_pk_f32_fp8(hB.z, true ), acc2[5]);
            acc2[6] = __builtin_elementwise_fma(w2, __builtin_amdgcn_cvt_pk_f32_fp8(hB.w, false), acc2[6]);
            acc2[7] = __builtin_elementwise_fma(w2, __builtin_amdgcn_cvt_pk_f32_fp8(hB.w, true ), acc2[7]);
        }
        e += 8;
    }

    // ---- fold the four quarters (same (h,chblk), disjoint edges) ----
    #pragma unroll
    for (int i = 0; i < 8; ++i) {
        acc2[i].x += __shfl_xor(acc2[i].x, 16, 64);
        acc2[i].y += __shfl_xor(acc2[i].y, 16, 64);
        acc2[i].x += __shfl_xor(acc2[i].x, 32, 64);
        acc2[i].y += __shfl_xor(acc2[i].y, 32, 64);
    }
    wsum += __shfl_xor(wsum, 16, 64);
    wsum += __shfl_xor(wsum, 32, 64);

    // ---- per-head softmax normalize (v_pk_mul) ----
    float winv = 1.0f / wsum;
    f32x2 winv2; winv2.x = winv; winv2.y = winv;
    #pragma unroll
    for (int i = 0; i < 8; ++i) acc2[i] *= winv2;

    // ---- sum over heads: lane = 2h + blk, fold bits 1..3 ----
    #pragma unroll
    for (int i = 0; i < 8; ++i) {
        acc2[i].x += __shfl_xor(acc2[i].x, 2, 64);
        acc2[i].y += __shfl_xor(acc2[i].y, 2, 64);
        acc2[i].x += __shfl_xor(acc2[i].x, 4, 64);
        acc2[i].y += __shfl_xor(acc2[i].y, 4, 64);
        acc2[i].x += __shfl_xor(acc2[i].x, 8, 64);
        acc2[i].y += __shfl_xor(acc2[i].y, 8, 64);
    }

    // ---- lane 0: channels 0..15, lane 1: channels 16..31 ----
    if (lane < 2) {
        const int c0 = lane * 16;
        const float4* bp4 = (const float4*)(b + c0);
        float4 b0 = bp4[0], b1 = bp4[1], b2 = bp4[2], b3 = bp4[3];
        float bb[16] = {b0.x, b0.y, b0.z, b0.w, b1.x, b1.y, b1.z, b1.w,
                        b2.x, b2.y, b2.z, b2.w, b3.x, b3.y, b3.z, b3.w};
        u32 d[8];
        #pragma unroll
        for (int i = 0; i < 8; ++i) {
            float v0 = acc2[i].x * 0.125f + bb[2 * i];
            float v1 = acc2[i].y * 0.125f + bb[2 * i + 1];
            v0 = v0 > 0.f ? v0 : (__expf(v0) - 1.f);
            v1 = v1 > 0.f ? v1 : (__expf(v1) - 1.f);
            d[i] = (u32)f2bf(v0) | ((u32)f2bf(v1) << 16);
        }
        uint4* op = (uint4*)(out + (size_t)dst * CH + c0);
        op[0] = make_uint4(d[0], d[1], d[2], d[3]);
        op[1] = make_uint4(d[4], d[5], d[6], d[7]);
    }
}

// ================= output head: 4 nodes/block (1 wave each), log_softmax
__global__ __launch_bounds__(256) void out_kernel(const u16* __restrict__ hf,
        const float* __restrict__ Wo, const float* __restrict__ bo,
        float* __restrict__ out) {
    const int wave = threadIdx.x >> 6;
    const int lane = threadIdx.x & 63;
    const int n    = blockIdx.x * 4 + wave;
    __shared__ float hs[4][CH];
    if (n < N_NODES && lane < CH) hs[wave][lane] = bflo((u32)hf[n * CH + lane]);
    __syncthreads();
    if (n >= N_NODES) return;
    float logit = -INFINITY;
    if (lane < OUT_C) {
        float a = bo[lane];
        #pragma unroll
        for (int k = 0; k < CH; ++k) a += hs[wave][k] * Wo[k * OUT_C + lane];
        logit = a;
    }
    float m = logit;
    #pragma unroll
    for (int off = 32; off; off >>= 1) m = fmaxf(m, __shfl_xor(m, off, 64));
    float ex = (lane < OUT_C) ? __expf(logit - m) : 0.f;
    float ssum = ex;
    #pragma unroll
    for (int off = 32; off; off >>= 1) ssum += __shfl_xor(ssum, off, 64);
    if (lane < OUT_C) out[(size_t)n * OUT_C + lane] = logit - m - __logf(ssum);
}

extern "C" void kernel_launch(void* const* d_in, const int* in_sizes, int n_in,
                              void* d_out, int out_size, void* d_ws, size_t ws_size,
                              hipStream_t stream) {
    const float* x      = (const float*)d_in[0];
    const int*   ei     = (const int*)  d_in[1];
    const float* W1     = (const float*)d_in[2];
    const float* a_src1 = (const float*)d_in[3];
    const float* a_dst1 = (const float*)d_in[4];
    const float* b1     = (const float*)d_in[5];
    const float* W2     = (const float*)d_in[6];
    const float* a_src2 = (const float*)d_in[7];
    const float* a_dst2 = (const float*)d_in[8];
    const float* b2     = (const float*)d_in[9];
    const float* Wo     = (const float*)d_in[10];
    const float* bo     = (const float*)d_in[11];
    float* out = (float*)d_out;

    // workspace carve-up (256B-aligned)
    char* ws = (char*)d_ws;
    size_t off = 0;
    auto carve = [&](size_t bytes) { char* p = ws + off; off += (bytes + 255) & ~(size_t)255; return p; };
    u8*    ht8     = (u8*)   carve((size_t)N_NODES * HC);          // 12.8 MB (fp8, head-major)
    u16*   Wt      = (u16*)  carve((size_t)HC * F_IN * 2);         // 128 KB (bf16 W1^T)
    u16*   W2t     = (u16*)  carve((size_t)HC * CH * 2);           // 16 KB (bf16 W2^T)
    float* asrc    = (float*)carve((size_t)N_NODES * NHEAD * 4);   // 1.6 MB
    float* adst    = (float*)carve((size_t)N_NODES * NHEAD * 4);
    u16*   hmid    = (u16*)  carve((size_t)N_PAD * CH * 2);        // 3.2 MB (bf16)
    u16*   hout    = (u16*)  carve((size_t)N_NODES * CH * 2);      // 3.2 MB (bf16)
    int*   deg     = (int*)  carve((size_t)N_NODES * 4);
    int*   rowptr  = (int*)  carve((size_t)(N_NODES + 1) * 4);
    int*   cursor  = (int*)  carve((size_t)N_NODES * 4);
    u16*   csr_src = (u16*)  carve((size_t)E_TOT * 2);             // 1.7 MB (u16)
    int*   partials= (int*)  carve((size_t)SCAN_BLOCKS * 4);

    const int g_cvt   = G_BIN + G_WCVT + G_WCVT2;            // 3616
    const int g_gemm  = (N_NODES + 31) / 32;                 // 1563
    const int g_attn  = (N_NODES * 64 + 255) / 256;          // 12500 (wave/dst)
    const int g_out   = (N_NODES + 3) / 4;                   // 12500

    // ---------- prep + CSR build ----------
    (void)hipMemsetAsync(deg, 0, (size_t)N_NODES * 4, stream);
    cvt_kernel<<<g_cvt, 256, 0, stream>>>(W1, Wt, W2, W2t, ei, deg);
    scan1_kernel<<<SCAN_BLOCKS, 256, 0, stream>>>(deg, rowptr, partials);
    scan2_kernel<<<1, 256, 0, stream>>>(partials);
    scan3_kernel<<<SCAN_BLOCKS, 256, 0, stream>>>(rowptr, cursor, partials);
    scatter_kernel<<<G_BIN, 256, 0, stream>>>(ei, cursor, csr_src);

    // ---------- layer 1 (alpha fused into gemm epilogue) ----------
    gemm1_mfma<<<g_gemm, 256, 0, stream>>>(x, Wt, a_src1, a_dst1, ht8, asrc, adst);
    attn_kernel<<<g_attn, 256, 0, stream>>>(rowptr, csr_src, asrc, adst, ht8, b1, hmid);

    // ---------- layer 2 ----------
    gemm2_mfma<<<g_gemm, 256, 0, stream>>>(hmid, W2t, a_src2, a_dst2, ht8, asrc, adst);
    attn_kernel<<<g_attn, 256, 0, stream>>>(rowptr, csr_src, asrc, adst, ht8, b2, hout);

    // ---------- output head ----------
    out_kernel<<<g_out, 256, 0, stream>>>(hout, Wo, bo, out);
}

// Round 7
// 317.219 us; speedup vs baseline: 1.2229x; 1.1371x over previous
//
#include <hip/hip_runtime.h>
#include <math.h>

#define N_NODES 50000
#define N_PAD   50016                 // padded to 32-row gemm tiles
#define N_EDGES 800000
#define E_TOT   (N_EDGES + N_NODES)   // edges + self-loops = 850000
#define F_IN    256
#define NHEAD   8
#define CH      32
#define HC      256                   // NHEAD*CH
#define OUT_C   40
#define NEG_SLOPE 0.2f
#define CAP     64                    // bucket capacity per dst (deg~Pois(16)+1)
#define G_WCVT  ((HC * F_IN + 255) / 256)            // 256
#define G_WCVT2 ((HC * CH + 255) / 256)              // 32
#define NRANGE  8                     // XCD count: dst-range affinity bins
#define RANGE_SZ (N_NODES / NRANGE)   // 6250
#define BIN_CHUNK 2048
#define G_BINCH ((E_TOT + BIN_CHUNK - 1) / BIN_CHUNK)   // 416
#define G_BIN   (G_BINCH * NRANGE)                      // 3328

typedef unsigned short u16;
typedef unsigned int   u32;
typedef unsigned char  u8;
typedef __attribute__((ext_vector_type(8))) short bf16x8;   // 4 VGPRs
typedef __attribute__((ext_vector_type(4))) float f32x4;
typedef __attribute__((ext_vector_type(2))) float f32x2;

__device__ __forceinline__ u16 f2bf(float f) {
    union { u32 u; float f; } x; x.f = f;
    u32 u = x.u;
    return (u16)((u + 0x7fffu + ((u >> 16) & 1u)) >> 16);   // round-nearest-even
}
__device__ __forceinline__ float bflo(u32 v) {
    union { u32 u; float f; } x; x.u = v << 16; return x.f;
}
// fp8 e4m3 encode (1 byte) / packed decode (2 floats per op) — gfx950 native
__device__ __forceinline__ u8 f2fp8(float f) {
    return (u8)(__builtin_amdgcn_cvt_pk_fp8_f32(f, f, 0, false) & 0xff);
}

// ht8 is fp8 e4m3 in NATURAL (head-major) layout: ht8[node*256 + h*32 + c].
// gemm stores are identity; in attn a 16-lane quarter reads one row as uint4.
// NOTE: f2fp8 of finite inputs saturates (never emits NaN bytes) — attn's
// stale-prefetch-register trick relies on decoded fp8 always being finite.
// r22: CSR build collapsed to ONE pass — fixed-capacity buckets
// csr_src[dst*CAP + atomicAdd(cursor[dst])]; cursor doubles as degree.
// Kills deg pass + scan1/2/3 (launches 10->7, ei re-reads 16x->8x). Each
// dst's bucket = 128B (2 lines) -> XCD-binned stores get full line reuse.

// ===== fused prep: XCD-affine binned bucket-scatter + W1^T + W2^T cvt
__global__ __launch_bounds__(256) void prep_kernel(const int* __restrict__ ei,
        int* __restrict__ cursor, u16* __restrict__ csr_src,
        const float* __restrict__ W1, u16* __restrict__ Wt,
        const float* __restrict__ W2, u16* __restrict__ W2t) {
    int b = blockIdx.x;
    if (b < G_BIN) {                  // binned one-pass scatter
        const int r  = b & (NRANGE - 1);
        const int ch = b >> 3;
        const int lo = r * RANGE_SZ, hi = lo + RANGE_SZ;
        int j0 = ch * BIN_CHUNK + threadIdx.x;
        #pragma unroll
        for (int i = 0; i < BIN_CHUNK / 256; ++i) {
            int j = j0 + i * 256;
            if (j < E_TOT) {
                int d = (j < N_EDGES) ? ei[N_EDGES + j] : (j - N_EDGES);
                if (d >= lo && d < hi) {
                    int s = (j < N_EDGES) ? ei[j] : d;
                    int pos = atomicAdd(&cursor[d], 1);
                    if (pos < CAP) csr_src[d * CAP + pos] = (u16)s;
                }
            }
        }
    } else if (b < G_BIN + G_WCVT) {
        int t = (b - G_BIN) * 256 + threadIdx.x;     // 65536 total
        int n = t & 255, k = t >> 8;                 // coalesced reads
        Wt[(size_t)n * F_IN + k] = f2bf(W1[(size_t)k * HC + n]);
    } else {
        int t = (b - G_BIN - G_WCVT) * 256 + threadIdx.x;  // 8192
        if (t >= HC * CH) return;
        int n = t & 255, k = t >> 8;
        W2t[(size_t)n * CH + k] = f2bf(W2[(size_t)k * HC + n]);
    }
}

// ===== shared GEMM epilogue: fp8 ht8 store + FUSED alpha (per-row per-head
// dot with a_src/a_dst). Wave covers heads hA=nb>>5 (n=0,1) and hA+1 (n=2,3);
// channel c = n*16 + l16. Quad-local 16-lane xor-reduce; l16==0 stores.
__device__ __forceinline__ void gemm_epilogue(f32x4 acc[2][4], int row0, int quad,
        int l16, int nb, const float* __restrict__ a_src,
        const float* __restrict__ a_dst, u8* __restrict__ ht8,
        float* __restrict__ asrc, float* __restrict__ adst) {
    #pragma unroll
    for (int m = 0; m < 2; ++m) {
        #pragma unroll
        for (int r = 0; r < 4; ++r) {
            int row = row0 + m * 16 + quad * 4 + r;
            if (row < N_NODES) {
                u8* hr = ht8 + (size_t)row * HC;
                #pragma unroll
                for (int n = 0; n < 4; ++n)
                    hr[nb + n * 16 + l16] = f2fp8(acc[m][n][r]);
            }
        }
    }
    const int hA = nb >> 5;
    const float sA0 = a_src[hA * 32 + l16],       sA1 = a_src[hA * 32 + 16 + l16];
    const float sB0 = a_src[(hA + 1) * 32 + l16], sB1 = a_src[(hA + 1) * 32 + 16 + l16];
    const float dA0 = a_dst[hA * 32 + l16],       dA1 = a_dst[hA * 32 + 16 + l16];
    const float dB0 = a_dst[(hA + 1) * 32 + l16], dB1 = a_dst[(hA + 1) * 32 + 16 + l16];
    #pragma unroll
    for (int m = 0; m < 2; ++m) {
        #pragma unroll
        for (int r = 0; r < 4; ++r) {
            float pa = acc[m][0][r] * sA0 + acc[m][1][r] * sA1;
            float pb = acc[m][2][r] * sB0 + acc[m][3][r] * sB1;
            float qa = acc[m][0][r] * dA0 + acc[m][1][r] * dA1;
            float qb = acc[m][2][r] * dB0 + acc[m][3][r] * dB1;
            #pragma unroll
            for (int off = 1; off < 16; off <<= 1) {
                pa += __shfl_xor(pa, off, 64);
                pb += __shfl_xor(pb, off, 64);
                qa += __shfl_xor(qa, off, 64);
                qb += __shfl_xor(qb, off, 64);
            }
            int row = row0 + m * 16 + quad * 4 + r;
            if (l16 == 0 && row < N_NODES) {
                asrc[row * NHEAD + hA]     = pa;
                asrc[row * NHEAD + hA + 1] = pb;
                adst[row * NHEAD + hA]     = qa;
                adst[row * NHEAD + hA + 1] = qb;
            }
        }
    }
}

// ================= GEMM1: ht8 = fp8(x @ W1) + fused alpha, LDS-staged A.
// Block coalesced-loads its 32x256 fp32 x-tile (contiguous 32KB), packs bf16
// into 16KB LDS with XOR swizzle (G4: byte ^= (row&7)<<4), one barrier, MFMA.
__global__ __launch_bounds__(256) void gemm1_mfma(const float* __restrict__ x,
        const u16* __restrict__ Wt, const float* __restrict__ a_src,
        const float* __restrict__ a_dst, u8* __restrict__ ht8,
        float* __restrict__ asrc, float* __restrict__ adst) {
    __shared__ u16 As[32 * 256];          // 16 KB bf16, swizzled
    const int row0 = blockIdx.x * 32;
    const int t    = threadIdx.x;

    {   // stage: 8 threads per row, float4-contiguous per wave
        const int r   = t >> 3;                       // 0..31
        const int sub = t & 7;
        const int gr  = min(row0 + r, N_NODES - 1);   // clamp pad rows
        const float4* xr = (const float4*)(x + (size_t)gr * F_IN);
        const int sw = (r & 7) << 4;
        char* Ar = (char*)As + r * 512;
        #pragma unroll
        for (int i = 0; i < 8; ++i) {
            int f4 = i * 8 + sub;                     // float4 idx 0..63
            float4 v = xr[f4];
            u32 lo = (u32)f2bf(v.x) | ((u32)f2bf(v.y) << 16);
            u32 hi = (u32)f2bf(v.z) | ((u32)f2bf(v.w) << 16);
            *(uint2*)(Ar + ((f4 * 8) ^ sw)) = make_uint2(lo, hi);
        }
    }
    __syncthreads();

    const int wave = t >> 6;
    const int lane = t & 63;
    const int l16  = lane & 15;
    const int quad = lane >> 4;
    const int nb   = wave * 64;
    const int swr  = (l16 & 7) << 4;
    const char* Ab = (const char*)As;

    f32x4 acc[2][4];
    #pragma unroll
    for (int m = 0; m < 2; ++m)
        #pragma unroll
        for (int n = 0; n < 4; ++n) acc[m][n] = (f32x4){0.f, 0.f, 0.f, 0.f};

    const u16* bp = Wt + (size_t)(nb + l16) * F_IN;   // N-tile stride 16*F_IN

    #pragma unroll 1
    for (int k0 = 0; k0 < F_IN; k0 += 32) {
        const int ko = k0 + quad * 8;
        bf16x8 a0 = *(const bf16x8*)(Ab + l16 * 512 + ((ko * 2) ^ swr));
        bf16x8 a1 = *(const bf16x8*)(Ab + (16 + l16) * 512 + ((ko * 2) ^ swr));
        bf16x8 b0 = *(const bf16x8*)(bp + 0 * 16 * F_IN + ko);
        bf16x8 b1 = *(const bf16x8*)(bp + 1 * 16 * F_IN + ko);
        bf16x8 b2 = *(const bf16x8*)(bp + 2 * 16 * F_IN + ko);
        bf16x8 b3 = *(const bf16x8*)(bp + 3 * 16 * F_IN + ko);
        acc[0][0] = __builtin_amdgcn_mfma_f32_16x16x32_bf16(a0, b0, acc[0][0], 0, 0, 0);
        acc[0][1] = __builtin_amdgcn_mfma_f32_16x16x32_bf16(a0, b1, acc[0][1], 0, 0, 0);
        acc[0][2] = __builtin_amdgcn_mfma_f32_16x16x32_bf16(a0, b2, acc[0][2], 0, 0, 0);
        acc[0][3] = __builtin_amdgcn_mfma_f32_16x16x32_bf16(a0, b3, acc[0][3], 0, 0, 0);
        acc[1][0] = __builtin_amdgcn_mfma_f32_16x16x32_bf16(a1, b0, acc[1][0], 0, 0, 0);
        acc[1][1] = __builtin_amdgcn_mfma_f32_16x16x32_bf16(a1, b1, acc[1][1], 0, 0, 0);
        acc[1][2] = __builtin_amdgcn_mfma_f32_16x16x32_bf16(a1, b2, acc[1][2], 0, 0, 0);
        acc[1][3] = __builtin_amdgcn_mfma_f32_16x16x32_bf16(a1, b3, acc[1][3], 0, 0, 0);
    }
    gemm_epilogue(acc, row0, quad, l16, nb, a_src, a_dst, ht8, asrc, adst);
}

// ================= GEMM2: ht8 = fp8(hmb @ W2) + fused alpha, K=32 one step
__global__ __launch_bounds__(256) void gemm2_mfma(const u16* __restrict__ hmb,
        const u16* __restrict__ W2t, const float* __restrict__ a_src,
        const float* __restrict__ a_dst, u8* __restrict__ ht8,
        float* __restrict__ asrc, float* __restrict__ adst) {
    const int row0 = blockIdx.x * 32;
    const int t    = threadIdx.x;
    const int wave = t >> 6;
    const int lane = t & 63;
    const int l16  = lane & 15;
    const int quad = lane >> 4;
    const int nb   = wave * 64;
    const int ko   = quad * 8;

    const u16* a0p = hmb + (size_t)(row0 + l16) * CH;
    const u16* a1p = a0p + 16 * CH;
    const u16* bp  = W2t + (size_t)(nb + l16) * CH;

    bf16x8 a0 = *(const bf16x8*)(a0p + ko);
    bf16x8 a1 = *(const bf16x8*)(a1p + ko);
    bf16x8 b0 = *(const bf16x8*)(bp + 0 * 16 * CH + ko);
    bf16x8 b1 = *(const bf16x8*)(bp + 1 * 16 * CH + ko);
    bf16x8 b2 = *(const bf16x8*)(bp + 2 * 16 * CH + ko);
    bf16x8 b3 = *(const bf16x8*)(bp + 3 * 16 * CH + ko);

    f32x4 z = (f32x4){0.f, 0.f, 0.f, 0.f};
    f32x4 acc[2][4];
    acc[0][0] = __builtin_amdgcn_mfma_f32_16x16x32_bf16(a0, b0, z, 0, 0, 0);
    acc[0][1] = __builtin_amdgcn_mfma_f32_16x16x32_bf16(a0, b1, z, 0, 0, 0);
    acc[0][2] = __builtin_amdgcn_mfma_f32_16x16x32_bf16(a0, b2, z, 0, 0, 0);
    acc[0][3] = __builtin_amdgcn_mfma_f32_16x16x32_bf16(a0, b3, z, 0, 0, 0);
    acc[1][0] = __builtin_amdgcn_mfma_f32_16x16x32_bf16(a1, b0, z, 0, 0, 0);
    acc[1][1] = __builtin_amdgcn_mfma_f32_16x16x32_bf16(a1, b1, z, 0, 0, 0);
    acc[1][2] = __builtin_amdgcn_mfma_f32_16x16x32_bf16(a1, b2, z, 0, 0, 0);
    acc[1][3] = __builtin_amdgcn_mfma_f32_16x16x32_bf16(a1, b3, z, 0, 0, 0);

    gemm_epilogue(acc, row0, quad, l16, nb, a_src, a_dst, ht8, asrc, adst);
}

// ================= fused attention: one WAVE per dst node, QUARTER per edge.
// Proven r3 loop body. r22: bucket CSR — p0 = dst*CAP, p1 = p0 + deg[dst].
__global__ __launch_bounds__(256) void attn_kernel(const int* __restrict__ degp,
        const u16* __restrict__ csr_src, const float* __restrict__ asrc,
        const float* __restrict__ adst, const u8* __restrict__ ht8,
        const float* __restrict__ b, u16* __restrict__ out) {
    const int wid = (blockIdx.x * 256 + threadIdx.x) >> 6;   // dst node
    if (wid >= N_NODES) return;
    const int dst  = wid;
    const int lane = threadIdx.x & 63;
    const int q    = lane >> 4;          // quarter -> edge offset
    const int l16  = lane & 15;
    const int h    = l16 >> 1;           // owned head
    const float ad_own = adst[dst * NHEAD + h];
    const u8* hbase = ht8 + l16 * 16;    // this lane's 16B slice of each row

    f32x2 acc2[8];
    #pragma unroll
    for (int i = 0; i < 8; ++i) acc2[i] = (f32x2){0.f, 0.f};
    float wsum = 0.f;

    const int cnt = min(degp[dst], CAP);
    const int p0 = dst * CAP, p1 = p0 + cnt;
    const int nt = (cnt + 7) >> 3;       // uniform trips (8 edges per trip)

    float asA = -1e30f, asB = -1e30f;
    uint4 hvA = make_uint4(0u, 0u, 0u, 0u), hvB = make_uint4(0u, 0u, 0u, 0u);
    int e = p0 + q;                      // this quarter's edges: stride 4
    if (e < p1) {
        int s = (int)csr_src[e];
        asA = asrc[s * NHEAD + h];
        hvA = *(const uint4*)(hbase + ((size_t)s << 8));
    }
    if (e + 4 < p1) {
        int s = (int)csr_src[e + 4];
        asB = asrc[s * NHEAD + h];
        hvB = *(const uint4*)(hbase + ((size_t)s << 8));
    }

    for (int it = 0; it < nt; ++it) {
        float aA = asA; uint4 hA = hvA;
        float aB = asB; uint4 hB = hvB;
        asA = -1e30f; asB = -1e30f;
        if (e + 8 < p1) {                 // prefetch next trip (predicated)
            int s = (int)csr_src[e + 8];
            asA = asrc[s * NHEAD + h];
            hvA = *(const uint4*)(hbase + ((size_t)s << 8));
        }
        if (e + 12 < p1) {
            int s = (int)csr_src[e + 12];
            asB = asrc[s * NHEAD + h];
            hvB = *(const uint4*)(hbase + ((size_t)s << 8));
        }
        {   // consume A (edge e); invalid slots: w==0, finite hv -> no-op
            float x = aA + ad_own;
            x = x > 0.f ? x : NEG_SLOPE * x;
            float w = __expf(x);
            wsum += w;
            f32x2 w2; w2.x = w; w2.y = w;
            acc2[0] = __builtin_elementwise_fma(w2, __builtin_amdgcn_cvt_pk_f32_fp8(hA.x, false), acc2[0]);
            acc2[1] = __builtin_elementwise_fma(w2, __builtin_amdgcn_cvt_pk_f32_fp8(hA.x, true ), acc2[1]);
            acc2[2] = __builtin_elementwise_fma(w2, __builtin_amdgcn_cvt_pk_f32_fp8(hA.y, false), acc2[2]);
            acc2[3] = __builtin_elementwise_fma(w2, __builtin_amdgcn_cvt_pk_f32_fp8(hA.y, true ), acc2[3]);
            acc2[4] = __builtin_elementwise_fma(w2, __builtin_amdgcn_cvt_pk_f32_fp8(hA.z, false), acc2[4]);
            acc2[5] = __builtin_elementwise_fma(w2, __builtin_amdgcn_cvt_pk_f32_fp8(hA.z, true ), acc2[5]);
            acc2[6] = __builtin_elementwise_fma(w2, __builtin_amdgcn_cvt_pk_f32_fp8(hA.w, false), acc2[6]);
            acc2[7] = __builtin_elementwise_fma(w2, __builtin_amdgcn_cvt_pk_f32_fp8(hA.w, true ), acc2[7]);
        }
        {   // consume B (edge e+4)
            float x = aB + ad_own;
            x = x > 0.f ? x : NEG_SLOPE * x;
            float w = __expf(x);
            wsum += w;
            f32x2 w2; w2.x = w; w2.y = w;
            acc2[0] = __builtin_elementwise_fma(w2, __builtin_amdgcn_cvt_pk_f32_fp8(hB.x, false), acc2[0]);
            acc2[1] = __builtin_elementwise_fma(w2, __builtin_amdgcn_cvt_pk_f32_fp8(hB.x, true ), acc2[1]);
            acc2[2] = __builtin_elementwise_fma(w2, __builtin_amdgcn_cvt_pk_f32_fp8(hB.y, false), acc2[2]);
            acc2[3] = __builtin_elementwise_fma(w2, __builtin_amdgcn_cvt_pk_f32_fp8(hB.y, true ), acc2[3]);
            acc2[4] = __builtin_elementwise_fma(w2, __builtin_amdgcn_cvt_pk_f32_fp8(hB.z, false), acc2[4]);
            acc2[5] = __builtin_elementwise_fma(w2, __builtin_amdgcn_cvt_pk_f32_fp8(hB.z, true ), acc2[5]);
            acc2[6] = __builtin_elementwise_fma(w2, __builtin_amdgcn_cvt_pk_f32_fp8(hB.w, false), acc2[6]);
            acc2[7] = __builtin_elementwise_fma(w2, __builtin_amdgcn_cvt_pk_f32_fp8(hB.w, true ), acc2[7]);
        }
        e += 8;
    }

    // ---- fold the four quarters (same (h,chblk), disjoint edges) ----
    #pragma unroll
    for (int i = 0; i < 8; ++i) {
        acc2[i].x += __shfl_xor(acc2[i].x, 16, 64);
        acc2[i].y += __shfl_xor(acc2[i].y, 16, 64);
        acc2[i].x += __shfl_xor(acc2[i].x, 32, 64);
        acc2[i].y += __shfl_xor(acc2[i].y, 32, 64);
    }
    wsum += __shfl_xor(wsum, 16, 64);
    wsum += __shfl_xor(wsum, 32, 64);

    // ---- per-head softmax normalize (v_pk_mul) ----
    float winv = 1.0f / wsum;
    f32x2 winv2; winv2.x = winv; winv2.y = winv;
    #pragma unroll
    for (int i = 0; i < 8; ++i) acc2[i] *= winv2;

    // ---- sum over heads: lane = 2h + blk, fold bits 1..3 ----
    #pragma unroll
    for (int i = 0; i < 8; ++i) {
        acc2[i].x += __shfl_xor(acc2[i].x, 2, 64);
        acc2[i].y += __shfl_xor(acc2[i].y, 2, 64);
        acc2[i].x += __shfl_xor(acc2[i].x, 4, 64);
        acc2[i].y += __shfl_xor(acc2[i].y, 4, 64);
        acc2[i].x += __shfl_xor(acc2[i].x, 8, 64);
        acc2[i].y += __shfl_xor(acc2[i].y, 8, 64);
    }

    // ---- lane 0: channels 0..15, lane 1: channels 16..31 ----
    if (lane < 2) {
        const int c0 = lane * 16;
        const float4* bp4 = (const float4*)(b + c0);
        float4 b0 = bp4[0], b1 = bp4[1], b2 = bp4[2], b3 = bp4[3];
        float bb[16] = {b0.x, b0.y, b0.z, b0.w, b1.x, b1.y, b1.z, b1.w,
                        b2.x, b2.y, b2.z, b2.w, b3.x, b3.y, b3.z, b3.w};
        u32 d[8];
        #pragma unroll
        for (int i = 0; i < 8; ++i) {
            float v0 = acc2[i].x * 0.125f + bb[2 * i];
            float v1 = acc2[i].y * 0.125f + bb[2 * i + 1];
            v0 = v0 > 0.f ? v0 : (__expf(v0) - 1.f);
            v1 = v1 > 0.f ? v1 : (__expf(v1) - 1.f);
            d[i] = (u32)f2bf(v0) | ((u32)f2bf(v1) << 16);
        }
        uint4* op = (uint4*)(out + (size_t)dst * CH + c0);
        op[0] = make_uint4(d[0], d[1], d[2], d[3]);
        op[1] = make_uint4(d[4], d[5], d[6], d[7]);
    }
}

// ================= output head: 4 nodes/block (1 wave each), log_softmax
__global__ __launch_bounds__(256) void out_kernel(const u16* __restrict__ hf,
        const float* __restrict__ Wo, const float* __restrict__ bo,
        float* __restrict__ out) {
    const int wave = threadIdx.x >> 6;
    const int lane = threadIdx.x & 63;
    const int n    = blockIdx.x * 4 + wave;
    __shared__ float hs[4][CH];
    if (n < N_NODES && lane < CH) hs[wave][lane] = bflo((u32)hf[n * CH + lane]);
    __syncthreads();
    if (n >= N_NODES) return;
    float logit = -INFINITY;
    if (lane < OUT_C) {
        float a = bo[lane];
        #pragma unroll
        for (int k = 0; k < CH; ++k) a += hs[wave][k] * Wo[k * OUT_C + lane];
        logit = a;
    }
    float m = logit;
    #pragma unroll
    for (int off = 32; off; off >>= 1) m = fmaxf(m, __shfl_xor(m, off, 64));
    float ex = (lane < OUT_C) ? __expf(logit - m) : 0.f;
    float ssum = ex;
    #pragma unroll
    for (int off = 32; off; off >>= 1) ssum += __shfl_xor(ssum, off, 64);
    if (lane < OUT_C) out[(size_t)n * OUT_C + lane] = logit - m - __logf(ssum);
}

extern "C" void kernel_launch(void* const* d_in, const int* in_sizes, int n_in,
                              void* d_out, int out_size, void* d_ws, size_t ws_size,
                              hipStream_t stream) {
    const float* x      = (const float*)d_in[0];
    const int*   ei     = (const int*)  d_in[1];
    const float* W1     = (const float*)d_in[2];
    const float* a_src1 = (const float*)d_in[3];
    const float* a_dst1 = (const float*)d_in[4];
    const float* b1     = (const float*)d_in[5];
    const float* W2     = (const float*)d_in[6];
    const float* a_src2 = (const float*)d_in[7];
    const float* a_dst2 = (const float*)d_in[8];
    const float* b2     = (const float*)d_in[9];
    const float* Wo     = (const float*)d_in[10];
    const float* bo     = (const float*)d_in[11];
    float* out = (float*)d_out;

    // workspace carve-up (256B-aligned)
    char* ws = (char*)d_ws;
    size_t off = 0;
    auto carve = [&](size_t bytes) { char* p = ws + off; off += (bytes + 255) & ~(size_t)255; return p; };
    u8*    ht8     = (u8*)   carve((size_t)N_NODES * HC);          // 12.8 MB (fp8, head-major)
    u16*   Wt      = (u16*)  carve((size_t)HC * F_IN * 2);         // 128 KB (bf16 W1^T)
    u16*   W2t     = (u16*)  carve((size_t)HC * CH * 2);           // 16 KB (bf16 W2^T)
    float* asrc    = (float*)carve((size_t)N_NODES * NHEAD * 4);   // 1.6 MB
    float* adst    = (float*)carve((size_t)N_NODES * NHEAD * 4);
    u16*   hmid    = (u16*)  carve((size_t)N_PAD * CH * 2);        // 3.2 MB (bf16)
    u16*   hout    = (u16*)  carve((size_t)N_NODES * CH * 2);      // 3.2 MB (bf16)
    int*   cursor  = (int*)  carve((size_t)N_NODES * 4);           // doubles as deg
    u16*   csr_src = (u16*)  carve((size_t)N_NODES * CAP * 2);     // 6.4 MB buckets

    const int g_prep  = G_BIN + G_WCVT + G_WCVT2;            // 3616
    const int g_gemm  = (N_NODES + 31) / 32;                 // 1563
    const int g_attn  = (N_NODES * 64 + 255) / 256;          // 12500 (wave/dst)
    const int g_out   = (N_NODES + 3) / 4;                   // 12500

    // ---------- prep: one-pass bucket CSR + W transposes ----------
    (void)hipMemsetAsync(cursor, 0, (size_t)N_NODES * 4, stream);
    prep_kernel<<<g_prep, 256, 0, stream>>>(ei, cursor, csr_src, W1, Wt, W2, W2t);

    // ---------- layer 1 (alpha fused into gemm epilogue) ----------
    gemm1_mfma<<<g_gemm, 256, 0, stream>>>(x, Wt, a_src1, a_dst1, ht8, asrc, adst);
    attn_kernel<<<g_attn, 256, 0, stream>>>(cursor, csr_src, asrc, adst, ht8, b1, hmid);

    // ---------- layer 2 ----------
    gemm2_mfma<<<g_gemm, 256, 0, stream>>>(hmid, W2t, a_src2, a_dst2, ht8, asrc, adst);
    attn_kernel<<<g_attn, 256, 0, stream>>>(cursor, csr_src, asrc, adst, ht8, b2, hout);

    // ---------- output head ----------
    out_kernel<<<g_out, 256, 0, stream>>>(hout, Wo, bo, out);
}